// Round 1
// baseline (558.876 us; speedup 1.0000x reference)
//
#include <hip/hip_runtime.h>
#include <hip/hip_bf16.h>

#define B_ 2
#define S_ 2048
#define E_ 2048
#define H_ 32
#define D_ 64

typedef __attribute__((ext_vector_type(8))) short short8_t;
typedef __attribute__((ext_vector_type(4))) float float4_t;

__device__ __forceinline__ short f2bf(float f) {
  union { float f; unsigned u; } x; x.f = f;
  unsigned r = x.u + 0x7fffu + ((x.u >> 16) & 1u);
  return (short)(r >> 16);
}

__device__ __forceinline__ void gload_lds16(const void* g, void* l) {
  __builtin_amdgcn_global_load_lds((const __attribute__((address_space(1))) void*)g,
                                   (__attribute__((address_space(3))) void*)l, 16, 0, 0);
}

// ---------------- cast fp32 -> bf16 ----------------
__global__ void cast_bf16_kernel(const float* __restrict__ in, short* __restrict__ out, int n4) {
  const int stride = gridDim.x * blockDim.x;
  for (int j = blockIdx.x * blockDim.x + threadIdx.x; j < n4; j += stride) {
    const float4 v = ((const float4*)in)[j];
    short4 r;
    r.x = f2bf(v.x); r.y = f2bf(v.y); r.z = f2bf(v.z); r.w = f2bf(v.w);
    ((short4*)out)[j] = r;
  }
}

// ---------------- GEMM: C[m][n] = sum_k A[m][k] * W[n][k] + bias[n] ----------------
// m97-structure: 128x128 tile, BK=32, 4 waves (2x2), global_load_lds width 16.
#define BM 128
#define BN 128
#define BK 32

template <int OUT_F32>
__global__ __launch_bounds__(256) void gemm_bt(const short* __restrict__ A,
                                               const short* __restrict__ Wt,
                                               const float* __restrict__ bias,
                                               void* __restrict__ Cout,
                                               int M, int N, int K) {
  __shared__ __align__(16) short As[BM * BK];
  __shared__ __align__(16) short Bs[BN * BK];
  const int tid = threadIdx.x;
  const int w = tid >> 6;
  const int lane = tid & 63;
  const int m0 = blockIdx.y * BM;
  const int n0 = blockIdx.x * BN;
  const int wr = w >> 1, wc = w & 1;
  const int r16 = lane & 15;
  const int c8 = (lane >> 4) * 8;

  // staging: chunk c = w*2+t covers rows c*16..c*16+15 (64B per row)
  const int srow = lane >> 2;        // 0..15
  const int scol = (lane & 3) * 8;   // 0,8,16,24
  const short* aG0 = A  + (size_t)(m0 + (w * 2 + 0) * 16 + srow) * K + scol;
  const short* aG1 = A  + (size_t)(m0 + (w * 2 + 1) * 16 + srow) * K + scol;
  const short* bG0 = Wt + (size_t)(n0 + (w * 2 + 0) * 16 + srow) * K + scol;
  const short* bG1 = Wt + (size_t)(n0 + (w * 2 + 1) * 16 + srow) * K + scol;
  short* aL0 = As + (w * 2 + 0) * 512;
  short* aL1 = As + (w * 2 + 1) * 512;
  short* bL0 = Bs + (w * 2 + 0) * 512;
  short* bL1 = Bs + (w * 2 + 1) * 512;

  float4_t acc[4][4];
#pragma unroll
  for (int mi = 0; mi < 4; ++mi)
#pragma unroll
    for (int ni = 0; ni < 4; ++ni) acc[mi][ni] = (float4_t){0.f, 0.f, 0.f, 0.f};

  for (int kt = 0; kt < K; kt += BK) {
    __syncthreads();
    gload_lds16(aG0, aL0);
    gload_lds16(aG1, aL1);
    gload_lds16(bG0, bL0);
    gload_lds16(bG1, bL1);
    aG0 += BK; aG1 += BK; bG0 += BK; bG1 += BK;
    __syncthreads();
    short8_t af[4], bf[4];
#pragma unroll
    for (int i = 0; i < 4; ++i)
      af[i] = *(const short8_t*)(As + (wr * 64 + i * 16 + r16) * BK + c8);
#pragma unroll
    for (int i = 0; i < 4; ++i)
      bf[i] = *(const short8_t*)(Bs + (wc * 64 + i * 16 + r16) * BK + c8);
#pragma unroll
    for (int mi = 0; mi < 4; ++mi)
#pragma unroll
      for (int ni = 0; ni < 4; ++ni)
        acc[mi][ni] = __builtin_amdgcn_mfma_f32_16x16x32_bf16(af[mi], bf[ni], acc[mi][ni], 0, 0, 0);
  }

  // epilogue: C row = m0+wr*64+mi*16+(lane>>4)*4+i, col = n0+wc*64+ni*16+(lane&15)
  const int colbase = n0 + wc * 64;
  const int rowbase = m0 + wr * 64 + (lane >> 4) * 4;
#pragma unroll
  for (int ni = 0; ni < 4; ++ni) {
    const int col = colbase + ni * 16 + r16;
    const float bv = bias[col];
#pragma unroll
    for (int mi = 0; mi < 4; ++mi) {
#pragma unroll
      for (int i = 0; i < 4; ++i) {
        const int row = rowbase + mi * 16 + i;
        const float v = acc[mi][ni][i] + bv;
        if (OUT_F32)
          ((float*)Cout)[(size_t)row * N + col] = v;
        else
          ((short*)Cout)[(size_t)row * N + col] = f2bf(v);
      }
    }
  }
}

// ---------------- causal flash attention ----------------
// Block: 4 waves, 64 q-rows (16 per wave). K/V tiles of 64 staged in LDS.
// Layouts verified per guide: A-frag lane holds row (lane&15), k=(lane>>4)*8+j;
// C/D: col=lane&15, row=(lane>>4)*4+i.
#define KPAD 72

__global__ __launch_bounds__(256) void attn_fwd(const short* __restrict__ Qg,
                                                const short* __restrict__ Kg,
                                                const short* __restrict__ Vg,
                                                short* __restrict__ Og) {
  __shared__ __align__(16) short Kl[64 * KPAD];
  __shared__ __align__(16) short Vt[64 * KPAD];   // transposed: Vt[d][k]
  __shared__ __align__(16) short Pl[4 * 16 * KPAD];
  const int tid = threadIdx.x, w = tid >> 6, lane = tid & 63;
  const int q0 = blockIdx.x * 64;
  const int bh = blockIdx.y;
  const int b = bh >> 5, h = bh & 31;  // H=32
  const int r16 = lane & 15, c8 = (lane >> 4) * 8, rg = (lane >> 4) * 4;

  // Q fragments (row = q0 + w*16 + (lane&15)), held for the whole block row
  const short* qrow = Qg + ((size_t)(b * S_ + q0 + w * 16 + r16)) * E_ + h * D_ + c8;
  short8_t qf0 = *(const short8_t*)qrow;
  short8_t qf1 = *(const short8_t*)(qrow + 32);

  float m_run[4] = {-1e30f, -1e30f, -1e30f, -1e30f};
  float l_run[4] = {0.f, 0.f, 0.f, 0.f};
  float4_t o[4];
#pragma unroll
  for (int db = 0; db < 4; ++db) o[db] = (float4_t){0.f, 0.f, 0.f, 0.f};

  const int nt = q0 / 64 + 1;  // causal: k-tiles 0..q0/64
  for (int t = 0; t < nt; ++t) {
    const int k0 = t * 64;
    __syncthreads();
    // stage K (row-major) and V (transposed) tiles
#pragma unroll
    for (int j = 0; j < 2; ++j) {
      const int idx = tid + j * 256;      // 0..511
      const int row = idx >> 3;           // 0..63
      const int cb = (idx & 7) * 8;       // 0..56
      const size_t goff = ((size_t)(b * S_ + k0 + row)) * E_ + h * D_ + cb;
      const short8_t kv = *(const short8_t*)(Kg + goff);
      *(short8_t*)(Kl + row * KPAD + cb) = kv;
      const short8_t vv = *(const short8_t*)(Vg + goff);
#pragma unroll
      for (int e = 0; e < 8; ++e) Vt[(cb + e) * KPAD + row] = vv[e];
    }
    __syncthreads();

    // S = Q K^T (16x64 per wave)
    float4_t s[4];
#pragma unroll
    for (int nb = 0; nb < 4; ++nb) {
      const short8_t k0f = *(const short8_t*)(Kl + (nb * 16 + r16) * KPAD + c8);
      const short8_t k1f = *(const short8_t*)(Kl + (nb * 16 + r16) * KPAD + 32 + c8);
      float4_t z = (float4_t){0.f, 0.f, 0.f, 0.f};
      z = __builtin_amdgcn_mfma_f32_16x16x32_bf16(qf0, k0f, z, 0, 0, 0);
      s[nb] = __builtin_amdgcn_mfma_f32_16x16x32_bf16(qf1, k1f, z, 0, 0, 0);
    }

    // scale + causal mask (only the diagonal tile actually masks)
    const bool need_mask = (k0 + 63 > q0 + w * 16);
#pragma unroll
    for (int nb = 0; nb < 4; ++nb)
#pragma unroll
      for (int i = 0; i < 4; ++i) {
        float v = s[nb][i] * 0.125f;
        if (need_mask && (k0 + nb * 16 + r16 > q0 + w * 16 + rg + i)) v = -1e30f;
        s[nb][i] = v;
      }

    // online softmax (row r lives in a 16-lane group at reg i=r&3)
#pragma unroll
    for (int i = 0; i < 4; ++i) {
      float mv = fmaxf(fmaxf(s[0][i], s[1][i]), fmaxf(s[2][i], s[3][i]));
#pragma unroll
      for (int off = 1; off < 16; off <<= 1) mv = fmaxf(mv, __shfl_xor(mv, off, 16));
      const float mnew = fmaxf(m_run[i], mv);
      const float alpha = __expf(m_run[i] - mnew);
      m_run[i] = mnew;
      float ps = 0.f;
#pragma unroll
      for (int nb = 0; nb < 4; ++nb) {
        const float p = __expf(s[nb][i] - mnew);
        s[nb][i] = p;
        ps += p;
      }
#pragma unroll
      for (int off = 1; off < 16; off <<= 1) ps += __shfl_xor(ps, off, 16);
      l_run[i] = l_run[i] * alpha + ps;
      o[0][i] *= alpha; o[1][i] *= alpha; o[2][i] *= alpha; o[3][i] *= alpha;
    }

    // P -> LDS (per-wave region), then re-fragment as MFMA A operand
    short* pw = Pl + w * 16 * KPAD;
#pragma unroll
    for (int nb = 0; nb < 4; ++nb)
#pragma unroll
      for (int i = 0; i < 4; ++i)
        pw[(rg + i) * KPAD + nb * 16 + r16] = f2bf(s[nb][i]);
    asm volatile("s_waitcnt lgkmcnt(0)" ::: "memory");
    const short8_t pa0 = *(const short8_t*)(pw + r16 * KPAD + c8);
    const short8_t pa1 = *(const short8_t*)(pw + r16 * KPAD + 32 + c8);

    // O += P V  (B-frag is a row-read of transposed V)
#pragma unroll
    for (int db = 0; db < 4; ++db) {
      const short8_t v0f = *(const short8_t*)(Vt + (db * 16 + r16) * KPAD + c8);
      const short8_t v1f = *(const short8_t*)(Vt + (db * 16 + r16) * KPAD + 32 + c8);
      o[db] = __builtin_amdgcn_mfma_f32_16x16x32_bf16(pa0, v0f, o[db], 0, 0, 0);
      o[db] = __builtin_amdgcn_mfma_f32_16x16x32_bf16(pa1, v1f, o[db], 0, 0, 0);
    }
  }

  // normalize + write [B,S,H,D]
#pragma unroll
  for (int i = 0; i < 4; ++i) {
    const float inv = 1.0f / l_run[i];
    const size_t row = (size_t)(b * S_ + q0 + w * 16 + rg + i);
#pragma unroll
    for (int db = 0; db < 4; ++db)
      Og[row * E_ + h * D_ + db * 16 + r16] = f2bf(o[db][i] * inv);
  }
}

// ---------------- launch ----------------
extern "C" void kernel_launch(void* const* d_in, const int* in_sizes, int n_in,
                              void* d_out, int out_size, void* d_ws, size_t ws_size,
                              hipStream_t stream) {
  const float* X  = (const float*)d_in[0];
  const float* Wq = (const float*)d_in[1];
  const float* bq = (const float*)d_in[2];
  const float* Wk = (const float*)d_in[3];
  const float* bk = (const float*)d_in[4];
  const float* Wv = (const float*)d_in[5];
  const float* bv = (const float*)d_in[6];
  const float* Wo = (const float*)d_in[7];
  const float* bo = (const float*)d_in[8];

  const size_t NX = (size_t)B_ * S_ * E_;  // 8388608
  const size_t NW = (size_t)E_ * E_;       // 4194304

  short* ws  = (short*)d_ws;
  short* Xb  = ws;          // [B*S, E] bf16
  short* Wb  = Xb + NX;     // one weight buffer, reused per GEMM
  short* Qb  = Wb + NW;
  short* Kb  = Qb + NX;
  short* Vb  = Kb + NX;
  short* Ab  = Xb;          // attention output reuses X (dead after V gemm)
  // total ws use: (4*NX + NW)*2 = ~75.5 MB

  const int M = B_ * S_;
  dim3 gg(E_ / BN, M / BM);   // (16, 32)
  dim3 ga(S_ / 64, B_ * H_);  // (32, 64)

  cast_bf16_kernel<<<2048, 256, 0, stream>>>(X, Xb, (int)(NX / 4));

  cast_bf16_kernel<<<1024, 256, 0, stream>>>(Wq, Wb, (int)(NW / 4));
  gemm_bt<0><<<gg, 256, 0, stream>>>(Xb, Wb, bq, Qb, M, E_, E_);

  cast_bf16_kernel<<<1024, 256, 0, stream>>>(Wk, Wb, (int)(NW / 4));
  gemm_bt<0><<<gg, 256, 0, stream>>>(Xb, Wb, bk, Kb, M, E_, E_);

  cast_bf16_kernel<<<1024, 256, 0, stream>>>(Wv, Wb, (int)(NW / 4));
  gemm_bt<0><<<gg, 256, 0, stream>>>(Xb, Wb, bv, Vb, M, E_, E_);

  attn_fwd<<<ga, 256, 0, stream>>>(Qb, Kb, Vb, Ab);

  cast_bf16_kernel<<<1024, 256, 0, stream>>>(Wo, Wb, (int)(NW / 4));
  gemm_bt<1><<<gg, 256, 0, stream>>>(Ab, Wb, bo, d_out, M, E_, E_);
}

// Round 2
// 350.623 us; speedup vs baseline: 1.5939x; 1.5939x over previous
//
#include <hip/hip_runtime.h>
#include <hip/hip_bf16.h>

#define B_ 2
#define S_ 2048
#define E_ 2048
#define H_ 32
#define D_ 64

typedef __attribute__((ext_vector_type(8))) short short8_t;
typedef __attribute__((ext_vector_type(4))) float float4_t;

__device__ __forceinline__ short f2bf(float f) {
  union { float f; unsigned u; } x; x.f = f;
  unsigned r = x.u + 0x7fffu + ((x.u >> 16) & 1u);
  return (short)(r >> 16);
}

__device__ __forceinline__ void gload_lds16(const void* g, void* l) {
  __builtin_amdgcn_global_load_lds((const __attribute__((address_space(1))) void*)g,
                                   (__attribute__((address_space(3))) void*)l, 16, 0, 0);
}

// ---------------- cast fp32 -> bf16 ----------------
__global__ void cast_bf16_kernel(const float* __restrict__ in, short* __restrict__ out, int n4) {
  const int stride = gridDim.x * blockDim.x;
  for (int j = blockIdx.x * blockDim.x + threadIdx.x; j < n4; j += stride) {
    const float4 v = ((const float4*)in)[j];
    short4 r;
    r.x = f2bf(v.x); r.y = f2bf(v.y); r.z = f2bf(v.z); r.w = f2bf(v.w);
    ((short4*)out)[j] = r;
  }
}

// ---------------- GEMM: C[m][n] = sum_k A[m][k] * W[n][k] + bias[n] ----------------
// OUT: 0 = bf16 row-major, 1 = f32 row-major, 2 = bf16 transposed (V^T layout [b*E+n][S])
#define BM 128
#define BN 128
#define BK 32

template <int OUT>
__global__ __launch_bounds__(256) void gemm_bt(const short* __restrict__ A,
                                               const short* __restrict__ Wt,
                                               const float* __restrict__ bias,
                                               void* __restrict__ Cout,
                                               int M, int N, int K) {
  extern __shared__ __align__(16) short smem[];
  short* As = smem;
  short* Bs = smem + BM * BK;
  const int tid = threadIdx.x;
  const int w = tid >> 6;
  const int lane = tid & 63;
  const int m0 = blockIdx.y * BM;
  const int n0 = blockIdx.x * BN;
  const int wr = w >> 1, wc = w & 1;
  const int r16 = lane & 15;
  const int c8 = (lane >> 4) * 8;

  const int srow = lane >> 2;        // 0..15
  const int scol = (lane & 3) * 8;   // 0,8,16,24
  const short* aG0 = A  + (size_t)(m0 + (w * 2 + 0) * 16 + srow) * K + scol;
  const short* aG1 = A  + (size_t)(m0 + (w * 2 + 1) * 16 + srow) * K + scol;
  const short* bG0 = Wt + (size_t)(n0 + (w * 2 + 0) * 16 + srow) * K + scol;
  const short* bG1 = Wt + (size_t)(n0 + (w * 2 + 1) * 16 + srow) * K + scol;
  short* aL0 = As + (w * 2 + 0) * 512;
  short* aL1 = As + (w * 2 + 1) * 512;
  short* bL0 = Bs + (w * 2 + 0) * 512;
  short* bL1 = Bs + (w * 2 + 1) * 512;

  float4_t acc[4][4];
#pragma unroll
  for (int mi = 0; mi < 4; ++mi)
#pragma unroll
    for (int ni = 0; ni < 4; ++ni) acc[mi][ni] = (float4_t){0.f, 0.f, 0.f, 0.f};

  for (int kt = 0; kt < K; kt += BK) {
    __syncthreads();
    gload_lds16(aG0, aL0);
    gload_lds16(aG1, aL1);
    gload_lds16(bG0, bL0);
    gload_lds16(bG1, bL1);
    aG0 += BK; aG1 += BK; bG0 += BK; bG1 += BK;
    __syncthreads();
    short8_t af[4], bf[4];
#pragma unroll
    for (int i = 0; i < 4; ++i)
      af[i] = *(const short8_t*)(As + (wr * 64 + i * 16 + r16) * BK + c8);
#pragma unroll
    for (int i = 0; i < 4; ++i)
      bf[i] = *(const short8_t*)(Bs + (wc * 64 + i * 16 + r16) * BK + c8);
#pragma unroll
    for (int mi = 0; mi < 4; ++mi)
#pragma unroll
      for (int ni = 0; ni < 4; ++ni)
        acc[mi][ni] = __builtin_amdgcn_mfma_f32_16x16x32_bf16(af[mi], bf[ni], acc[mi][ni], 0, 0, 0);
  }

  const int rg = (lane >> 4) * 4;
  if (OUT == 2) {
    // transpose this wave's 64x64 quadrant through per-wave LDS, write V^T
    short* qt = smem + 2 * BM * BK + w * 4096;  // 64x64 shorts per wave
#pragma unroll
    for (int ni = 0; ni < 4; ++ni) {
      const float bv = bias[n0 + wc * 64 + ni * 16 + r16];
#pragma unroll
      for (int mi = 0; mi < 4; ++mi)
#pragma unroll
        for (int i = 0; i < 4; ++i)
          qt[(ni * 16 + r16) * 64 + mi * 16 + rg + i] = f2bf(acc[mi][ni][i] + bv);
    }
    asm volatile("s_waitcnt lgkmcnt(0)" ::: "memory");
    __builtin_amdgcn_sched_barrier(0);
    const int b = m0 >> 11;                      // S_=2048
    const int mloc = (m0 & (S_ - 1)) + wr * 64;  // col (s) base in V^T
    short* Vt = (short*)Cout;
#pragma unroll
    for (int p = 0; p < 8; ++p) {
      const int rowd = p * 8 + (lane >> 3);      // local n index 0..63
      const short8_t vv = *(const short8_t*)(qt + rowd * 64 + (lane & 7) * 8);
      *(short8_t*)(Vt + ((size_t)(b * E_ + n0 + wc * 64 + rowd)) * S_ + mloc + (lane & 7) * 8) = vv;
    }
  } else {
    const int colbase = n0 + wc * 64;
    const int rowbase = m0 + wr * 64 + rg;
#pragma unroll
    for (int ni = 0; ni < 4; ++ni) {
      const int col = colbase + ni * 16 + r16;
      const float bv = bias[col];
#pragma unroll
      for (int mi = 0; mi < 4; ++mi) {
#pragma unroll
        for (int i = 0; i < 4; ++i) {
          const int row = rowbase + mi * 16 + i;
          const float v = acc[mi][ni][i] + bv;
          if (OUT == 1)
            ((float*)Cout)[(size_t)row * N + col] = v;
          else
            ((short*)Cout)[(size_t)row * N + col] = f2bf(v);
        }
      }
    }
  }
}

// ---------------- causal flash attention ----------------
// 4 waves x 16 q-rows, KV tile = 128. K and V^T staged via global_load_lds
// (linear LDS + pre-swizzled global source); reads apply matching XOR.
#define KT 128
#define KP 136
#define SCALE_L2E 0.18033688f  // 0.125 * log2(e)

__global__ __launch_bounds__(256) void attn_fwd(const short* __restrict__ Qg,
                                                const short* __restrict__ Kg,
                                                const short* __restrict__ Vt,
                                                short* __restrict__ Og) {
  __shared__ __align__(16) short Kl[KT * 64];   // [kv][d], rows 128B, swizzled ^((row&7)<<4)
  __shared__ __align__(16) short Vl[64 * KT];   // [d][kv], rows 256B, swizzled ^((row&15)<<4)
  __shared__ __align__(16) short Pl[4 * 16 * KP];
  const int tid = threadIdx.x, w = tid >> 6, lane = tid & 63;
  const int bh = blockIdx.x;
  const int b = bh >> 5, h = bh & 31;
  const int qt = gridDim.y - 1 - blockIdx.y;   // heavy q-tiles dispatch first
  const int q0 = qt * 64;
  const int r16 = lane & 15, hi = lane >> 4, c8 = hi * 8, rg = hi * 4;

  const short* qrow = Qg + ((size_t)(b * S_ + q0 + w * 16 + r16)) * E_ + h * D_;
  const short8_t qf0 = *(const short8_t*)(qrow + c8);
  const short8_t qf1 = *(const short8_t*)(qrow + 32 + c8);

  float m_run[4] = {-1e30f, -1e30f, -1e30f, -1e30f};
  float l_run[4] = {0.f, 0.f, 0.f, 0.f};
  float4_t o[4];
#pragma unroll
  for (int db = 0; db < 4; ++db) o[db] = (float4_t){0.f, 0.f, 0.f, 0.f};

  // staging lane decomposition
  const int sr8 = lane >> 3, sc8 = lane & 7;    // K: 8 rows / instr
  const int sr4 = lane >> 4, sc16 = lane & 15;  // V: 4 rows / instr
  const char* Kgb = (const char*)(Kg + ((size_t)b * S_) * E_ + h * D_);
  const char* Vgb = (const char*)(Vt + ((size_t)bh * 64) * S_);

  const int nt = (q0 >> 7) + 1;
  for (int t = 0; t < nt; ++t) {
    const int k0 = t * KT;
    __syncthreads();
#pragma unroll
    for (int i = 0; i < 4; ++i) {
      const int kr = w * 32 + i * 8 + sr8;
      gload_lds16(Kgb + (size_t)(k0 + kr) * (E_ * 2) + ((sc8 * 16) ^ (sr8 << 4)),
                  Kl + (w * 32 + i * 8) * 64);
      const int vr = w * 16 + i * 4 + sr4;
      gload_lds16(Vgb + (size_t)vr * (S_ * 2) + k0 * 2 + ((sc16 * 16) ^ (((i * 4 + sr4) & 15) << 4)),
                  Vl + (w * 16 + i * 4) * KT);
    }
    __syncthreads();

    // S = Q K^T : 16 q-rows x 128 kv per wave
    float4_t s[8];
#pragma unroll
    for (int nb = 0; nb < 8; ++nb) {
      const int kr = nb * 16 + r16;
      const int x = (kr & 7) << 4;
      const short8_t k0f = *(const short8_t*)((const char*)Kl + kr * 128 + ((c8 * 2) ^ x));
      const short8_t k1f = *(const short8_t*)((const char*)Kl + kr * 128 + ((64 + c8 * 2) ^ x));
      float4_t z = (float4_t){0.f, 0.f, 0.f, 0.f};
      z = __builtin_amdgcn_mfma_f32_16x16x32_bf16(qf0, k0f, z, 0, 0, 0);
      s[nb] = __builtin_amdgcn_mfma_f32_16x16x32_bf16(qf1, k1f, z, 0, 0, 0);
    }

    const bool last = (t == nt - 1);
#pragma unroll
    for (int nb = 0; nb < 8; ++nb)
#pragma unroll
      for (int i = 0; i < 4; ++i) {
        float v = s[nb][i] * SCALE_L2E;
        if (last && (k0 + nb * 16 + r16 > q0 + w * 16 + rg + i)) v = -1e30f;
        s[nb][i] = v;
      }

    // online softmax (log2 domain), row r in 16-lane group, reg i
#pragma unroll
    for (int i = 0; i < 4; ++i) {
      float mv = s[0][i];
#pragma unroll
      for (int nb = 1; nb < 8; ++nb) mv = fmaxf(mv, s[nb][i]);
#pragma unroll
      for (int off = 1; off < 16; off <<= 1) mv = fmaxf(mv, __shfl_xor(mv, off, 16));
      const float mnew = fmaxf(m_run[i], mv);
      const float alpha = exp2f(m_run[i] - mnew);
      m_run[i] = mnew;
      float ps = 0.f;
#pragma unroll
      for (int nb = 0; nb < 8; ++nb) {
        const float p = exp2f(s[nb][i] - mnew);
        s[nb][i] = p;
        ps += p;
      }
#pragma unroll
      for (int off = 1; off < 16; off <<= 1) ps += __shfl_xor(ps, off, 16);
      l_run[i] = l_run[i] * alpha + ps;
      o[0][i] *= alpha; o[1][i] *= alpha; o[2][i] *= alpha; o[3][i] *= alpha;
    }

    // P -> per-wave LDS, re-fragment as MFMA A operand
    short* pw = Pl + w * 16 * KP;
#pragma unroll
    for (int nb = 0; nb < 8; ++nb)
#pragma unroll
      for (int i = 0; i < 4; ++i)
        pw[(rg + i) * KP + nb * 16 + r16] = f2bf(s[nb][i]);
    asm volatile("s_waitcnt lgkmcnt(0)" ::: "memory");
    __builtin_amdgcn_sched_barrier(0);
    short8_t pa[4];
#pragma unroll
    for (int kc = 0; kc < 4; ++kc)
      pa[kc] = *(const short8_t*)(pw + r16 * KP + kc * 32 + c8);

    // O += P V : B-frag rows are d (V^T), swizzled
#pragma unroll
    for (int db = 0; db < 4; ++db) {
      const int vr = db * 16 + r16;
      const int x = (vr & 15) << 4;
#pragma unroll
      for (int kc = 0; kc < 4; ++kc) {
        const short8_t vf = *(const short8_t*)((const char*)Vl + vr * 256 + ((kc * 64 + hi * 16) ^ x));
        o[db] = __builtin_amdgcn_mfma_f32_16x16x32_bf16(pa[kc], vf, o[db], 0, 0, 0);
      }
    }
  }

  // normalize + write [B,S,H,D]
#pragma unroll
  for (int i = 0; i < 4; ++i) {
    const float inv = 1.0f / l_run[i];
    const size_t row = (size_t)(b * S_ + q0 + w * 16 + rg + i);
#pragma unroll
    for (int db = 0; db < 4; ++db)
      Og[row * E_ + h * D_ + db * 16 + r16] = f2bf(o[db][i] * inv);
  }
}

// ---------------- launch ----------------
extern "C" void kernel_launch(void* const* d_in, const int* in_sizes, int n_in,
                              void* d_out, int out_size, void* d_ws, size_t ws_size,
                              hipStream_t stream) {
  const float* X  = (const float*)d_in[0];
  const float* Wq = (const float*)d_in[1];
  const float* bq = (const float*)d_in[2];
  const float* Wk = (const float*)d_in[3];
  const float* bk = (const float*)d_in[4];
  const float* Wv = (const float*)d_in[5];
  const float* bv = (const float*)d_in[6];
  const float* Wo = (const float*)d_in[7];
  const float* bo = (const float*)d_in[8];

  const size_t NX = (size_t)B_ * S_ * E_;
  const size_t NW = (size_t)E_ * E_;

  short* ws  = (short*)d_ws;
  short* Xb  = ws;
  short* Wb  = Xb + NX;
  short* Qb  = Wb + NW;
  short* Kb  = Qb + NX;
  short* Vb  = Kb + NX;   // holds V^T layout [b*E+n][S]
  short* Ab  = Xb;        // attention output reuses X

  const int M = B_ * S_;
  dim3 gg(E_ / BN, M / BM);
  dim3 ga(B_ * H_, S_ / 64);
  const size_t smem_g = (size_t)2 * BM * BK * 2;          // 16 KB
  const size_t smem_v = smem_g + (size_t)4 * 64 * 64 * 2; // 48 KB

  cast_bf16_kernel<<<2048, 256, 0, stream>>>(X, Xb, (int)(NX / 4));

  cast_bf16_kernel<<<1024, 256, 0, stream>>>(Wq, Wb, (int)(NW / 4));
  gemm_bt<0><<<gg, 256, smem_g, stream>>>(Xb, Wb, bq, Qb, M, E_, E_);

  cast_bf16_kernel<<<1024, 256, 0, stream>>>(Wk, Wb, (int)(NW / 4));
  gemm_bt<0><<<gg, 256, smem_g, stream>>>(Xb, Wb, bk, Kb, M, E_, E_);

  cast_bf16_kernel<<<1024, 256, 0, stream>>>(Wv, Wb, (int)(NW / 4));
  gemm_bt<2><<<gg, 256, smem_v, stream>>>(Xb, Wb, bv, Vb, M, E_, E_);

  attn_fwd<<<ga, 256, 0, stream>>>(Qb, Kb, Vb, Ab);

  cast_bf16_kernel<<<1024, 256, 0, stream>>>(Wo, Wb, (int)(NW / 4));
  gemm_bt<1><<<gg, 256, smem_g, stream>>>(Ab, Wb, bo, d_out, M, E_, E_);
}

// Round 4
// 286.070 us; speedup vs baseline: 1.9536x; 1.2257x over previous
//
#include <hip/hip_runtime.h>
#include <hip/hip_bf16.h>

#define B_ 2
#define S_ 2048
#define E_ 2048
#define H_ 32
#define D_ 64
#define SCALE_L2E 0.18033688f  // 0.125 * log2(e)

typedef __attribute__((ext_vector_type(8))) short short8_t;
typedef __attribute__((ext_vector_type(4))) float float4_t;
typedef __attribute__((ext_vector_type(16))) float f32x16;
typedef unsigned int uint;
typedef __attribute__((ext_vector_type(4))) uint uint4_t;

__device__ __forceinline__ short f2bf(float f) {
  union { float f; unsigned u; } x; x.f = f;
  unsigned r = x.u + 0x7fffu + ((x.u >> 16) & 1u);
  return (short)(r >> 16);
}

__device__ __forceinline__ void gload_lds16(const void* g, void* l) {
  __builtin_amdgcn_global_load_lds((const __attribute__((address_space(1))) void*)g,
                                   (__attribute__((address_space(3))) void*)l, 16, 0, 0);
}

__device__ __forceinline__ uint cvt_pk_bf16(float lo, float hi) {
  uint r;
  asm volatile("v_cvt_pk_bf16_f32 %0, %1, %2" : "=v"(r) : "v"(lo), "v"(hi));
  return r;
}

// a' = [a.lo | b.lo], b' = [a.hi | b.hi] across the lane<32 / lane>=32 split
__device__ __forceinline__ void pl32swap(uint& a, uint& b) {
  asm volatile("v_permlane32_swap_b32 %0, %1" : "+v"(a), "+v"(b));
}

__device__ __forceinline__ f32x16 zero16() {
  f32x16 v;
#pragma unroll
  for (int i = 0; i < 16; ++i) v[i] = 0.f;
  return v;
}

// ---------------- casts ----------------
__global__ void cast_bf16_kernel(const float* __restrict__ in, short* __restrict__ out, int n4) {
  const int stride = gridDim.x * blockDim.x;
  for (int j = blockIdx.x * blockDim.x + threadIdx.x; j < n4; j += stride) {
    const float4 v = ((const float4*)in)[j];
    short4 r;
    r.x = f2bf(v.x); r.y = f2bf(v.y); r.z = f2bf(v.z); r.w = f2bf(v.w);
    ((short4*)out)[j] = r;
  }
}

__global__ void cast3_bf16(const float* __restrict__ a, const float* __restrict__ b,
                           const float* __restrict__ c, short* __restrict__ out) {
  constexpr int n4 = (E_ * E_) / 4;  // 2^20
  const int stride = gridDim.x * blockDim.x;
  for (int j = blockIdx.x * blockDim.x + threadIdx.x; j < 3 * n4; j += stride) {
    const float* src = (j < n4) ? a : (j < 2 * n4 ? b : c);
    const int idx = j & (n4 - 1);
    const float4 v = ((const float4*)src)[idx];
    short4 r;
    r.x = f2bf(v.x); r.y = f2bf(v.y); r.z = f2bf(v.z); r.w = f2bf(v.w);
    ((short4*)out)[j] = r;
  }
}

// ---------------- fused QKV GEMM ----------------
// C[m][n] = sum_k X[m][k] * W[n][k] + bias; W = [Wq;Wk;Wv] (6144 rows).
// seg 0: Q row-major, scaled by SCALE_L2E. seg 1: K row-major. seg 2: V^T [b*E+n][S].
#define BM 128
#define BN 128
#define BK 32

__global__ __launch_bounds__(256) void gemm_qkv(const short* __restrict__ A,
                                                const short* __restrict__ Wt,
                                                const float* __restrict__ bq,
                                                const float* __restrict__ bk,
                                                const float* __restrict__ bv,
                                                short* __restrict__ Qb,
                                                short* __restrict__ Kb,
                                                short* __restrict__ Vb) {
  __shared__ __align__(16) short smem[2 * BM * BK + 4 * 64 * 64];
  short* As = smem;
  short* Bs = smem + BM * BK;
  const int K = E_, N = E_;
  const int tid = threadIdx.x;
  const int w = tid >> 6;
  const int lane = tid & 63;
  const int m0 = blockIdx.y * BM;
  const int n0 = blockIdx.x * BN;
  const int wr = w >> 1, wc = w & 1;
  const int r16 = lane & 15;
  const int c8 = (lane >> 4) * 8;

  const int srow = lane >> 2;
  const int scol = (lane & 3) * 8;
  const short* aG0 = A  + (size_t)(m0 + (w * 2 + 0) * 16 + srow) * K + scol;
  const short* aG1 = A  + (size_t)(m0 + (w * 2 + 1) * 16 + srow) * K + scol;
  const short* bG0 = Wt + (size_t)(n0 + (w * 2 + 0) * 16 + srow) * K + scol;
  const short* bG1 = Wt + (size_t)(n0 + (w * 2 + 1) * 16 + srow) * K + scol;
  short* aL0 = As + (w * 2 + 0) * 512;
  short* aL1 = As + (w * 2 + 1) * 512;
  short* bL0 = Bs + (w * 2 + 0) * 512;
  short* bL1 = Bs + (w * 2 + 1) * 512;

  float4_t acc[4][4];
#pragma unroll
  for (int mi = 0; mi < 4; ++mi)
#pragma unroll
    for (int ni = 0; ni < 4; ++ni) acc[mi][ni] = (float4_t){0.f, 0.f, 0.f, 0.f};

  for (int kt = 0; kt < K; kt += BK) {
    __syncthreads();
    gload_lds16(aG0, aL0);
    gload_lds16(aG1, aL1);
    gload_lds16(bG0, bL0);
    gload_lds16(bG1, bL1);
    aG0 += BK; aG1 += BK; bG0 += BK; bG1 += BK;
    __syncthreads();
    short8_t af[4], bf[4];
#pragma unroll
    for (int i = 0; i < 4; ++i)
      af[i] = *(const short8_t*)(As + (wr * 64 + i * 16 + r16) * BK + c8);
#pragma unroll
    for (int i = 0; i < 4; ++i)
      bf[i] = *(const short8_t*)(Bs + (wc * 64 + i * 16 + r16) * BK + c8);
#pragma unroll
    for (int mi = 0; mi < 4; ++mi)
#pragma unroll
      for (int ni = 0; ni < 4; ++ni)
        acc[mi][ni] = __builtin_amdgcn_mfma_f32_16x16x32_bf16(af[mi], bf[ni], acc[mi][ni], 0, 0, 0);
  }

  const int rg = (lane >> 4) * 4;
  const int seg = n0 >> 11;      // 0=Q, 1=K, 2=V
  const int ncol = n0 & 2047;
  if (seg == 2) {
    // transpose this wave's 64x64 quadrant through per-wave LDS, write V^T
    short* qt = smem + 2 * BM * BK + w * 4096;
#pragma unroll
    for (int ni = 0; ni < 4; ++ni) {
      const float bvv = bv[ncol + wc * 64 + ni * 16 + r16];
#pragma unroll
      for (int mi = 0; mi < 4; ++mi)
#pragma unroll
        for (int i = 0; i < 4; ++i)
          qt[(ni * 16 + r16) * 64 + mi * 16 + rg + i] = f2bf(acc[mi][ni][i] + bvv);
    }
    asm volatile("s_waitcnt lgkmcnt(0)" ::: "memory");
    __builtin_amdgcn_sched_barrier(0);
    const int b = m0 >> 11;
    const int mloc = (m0 & (S_ - 1)) + wr * 64;
#pragma unroll
    for (int p = 0; p < 8; ++p) {
      const int rowd = p * 8 + (lane >> 3);
      const short8_t vv = *(const short8_t*)(qt + rowd * 64 + (lane & 7) * 8);
      *(short8_t*)(Vb + ((size_t)(b * E_ + ncol + wc * 64 + rowd)) * S_ + mloc + (lane & 7) * 8) = vv;
    }
  } else {
    const float* bias = seg ? bk : bq;
    short* Out = seg ? Kb : Qb;
    const float sc = seg ? 1.0f : SCALE_L2E;
    const int colbase = ncol + wc * 64;
    const int rowbase = m0 + wr * 64 + rg;
#pragma unroll
    for (int ni = 0; ni < 4; ++ni) {
      const int col = colbase + ni * 16 + r16;
      const float bvv = bias[col];
#pragma unroll
      for (int mi = 0; mi < 4; ++mi)
#pragma unroll
        for (int i = 0; i < 4; ++i)
          Out[(size_t)(rowbase + mi * 16 + i) * N + col] = f2bf((acc[mi][ni][i] + bvv) * sc);
    }
  }
}

// ---------------- output-projection GEMM (f32 out) ----------------
__global__ __launch_bounds__(256) void gemm_o(const short* __restrict__ A,
                                              const short* __restrict__ Wt,
                                              const float* __restrict__ bias,
                                              float* __restrict__ Cout) {
  __shared__ __align__(16) short smem[2 * BM * BK];
  short* As = smem;
  short* Bs = smem + BM * BK;
  const int K = E_, N = E_;
  const int tid = threadIdx.x;
  const int w = tid >> 6;
  const int lane = tid & 63;
  const int m0 = blockIdx.y * BM;
  const int n0 = blockIdx.x * BN;
  const int wr = w >> 1, wc = w & 1;
  const int r16 = lane & 15;
  const int c8 = (lane >> 4) * 8;

  const int srow = lane >> 2;
  const int scol = (lane & 3) * 8;
  const short* aG0 = A  + (size_t)(m0 + (w * 2 + 0) * 16 + srow) * K + scol;
  const short* aG1 = A  + (size_t)(m0 + (w * 2 + 1) * 16 + srow) * K + scol;
  const short* bG0 = Wt + (size_t)(n0 + (w * 2 + 0) * 16 + srow) * K + scol;
  const short* bG1 = Wt + (size_t)(n0 + (w * 2 + 1) * 16 + srow) * K + scol;
  short* aL0 = As + (w * 2 + 0) * 512;
  short* aL1 = As + (w * 2 + 1) * 512;
  short* bL0 = Bs + (w * 2 + 0) * 512;
  short* bL1 = Bs + (w * 2 + 1) * 512;

  float4_t acc[4][4];
#pragma unroll
  for (int mi = 0; mi < 4; ++mi)
#pragma unroll
    for (int ni = 0; ni < 4; ++ni) acc[mi][ni] = (float4_t){0.f, 0.f, 0.f, 0.f};

  for (int kt = 0; kt < K; kt += BK) {
    __syncthreads();
    gload_lds16(aG0, aL0);
    gload_lds16(aG1, aL1);
    gload_lds16(bG0, bL0);
    gload_lds16(bG1, bL1);
    aG0 += BK; aG1 += BK; bG0 += BK; bG1 += BK;
    __syncthreads();
    short8_t af[4], bf[4];
#pragma unroll
    for (int i = 0; i < 4; ++i)
      af[i] = *(const short8_t*)(As + (wr * 64 + i * 16 + r16) * BK + c8);
#pragma unroll
    for (int i = 0; i < 4; ++i)
      bf[i] = *(const short8_t*)(Bs + (wc * 64 + i * 16 + r16) * BK + c8);
#pragma unroll
    for (int mi = 0; mi < 4; ++mi)
#pragma unroll
      for (int ni = 0; ni < 4; ++ni)
        acc[mi][ni] = __builtin_amdgcn_mfma_f32_16x16x32_bf16(af[mi], bf[ni], acc[mi][ni], 0, 0, 0);
  }

  const int rg = (lane >> 4) * 4;
  const int colbase = n0 + wc * 64;
  const int rowbase = m0 + wr * 64 + rg;
#pragma unroll
  for (int ni = 0; ni < 4; ++ni) {
    const int col = colbase + ni * 16 + r16;
    const float bvv = bias[col];
#pragma unroll
    for (int mi = 0; mi < 4; ++mi)
#pragma unroll
      for (int i = 0; i < 4; ++i)
        Cout[(size_t)(rowbase + mi * 16 + i) * N + col] = acc[mi][ni][i] + bvv;
  }
}

// ---------------- causal flash attention (swapped 32x32, 8 waves) ----------------
// Block: 8 waves x 32 q-rows (paired q-tiles p and 7-p). KV tile 64, double-buffered.
// S^T = mfma(K, Q): lane holds P[q=lane&31][kv=(r&3)+8(r>>2)+4*hi32 (+32)].
// PV:   O^T = mfma(V^T, P^T): col=lane&31=q (per-lane softmax stats apply), reg=d.
__global__ __launch_bounds__(512, 2) void attn_fwd(const short* __restrict__ Qg,
                                                   const short* __restrict__ Kg,
                                                   const short* __restrict__ Vt,
                                                   short* __restrict__ Og) {
  __shared__ __align__(16) short lds[16384];  // 2 bufs x (K 8KB + V^T 8KB)
  const int tid = threadIdx.x, w = tid >> 6, lane = tid & 63;
  const int l31 = lane & 31, hh = lane >> 5;
  const int bh = blockIdx.x;
  const int b = bh >> 5, h = bh & 31;
  const int pq = blockIdx.y;  // 0..3

  const char* Kgb = (const char*)(Kg + (size_t)b * S_ * E_ + h * D_);
  const char* Vgb = (const char*)(Vt + (size_t)bh * 64 * S_);

  // staging lane decomposition (wave-uniform LDS base, per-lane global src)
  const int srow = w * 8 + (lane >> 3);       // 0..63
  const int sb = (lane & 7) * 16;             // byte slot
  const int ssw = (srow & 7) << 4;

#pragma unroll 1
  for (int ph = 0; ph < 2; ++ph) {
    const int qt = ph ? (7 - pq) : pq;
    const int q0 = qt * 256;
    const int qwmin = q0 + w * 32;
    const int qg = qwmin + l31;

    // Q fragments: lane holds q-row l31, d = dblk*16 + hh*8 + j (scaled by SCALE_L2E already)
    const short* qr = Qg + ((size_t)(b * S_ + qg)) * E_ + h * D_;
    short8_t qf[4];
#pragma unroll
    for (int dblk = 0; dblk < 4; ++dblk)
      qf[dblk] = *(const short8_t*)(qr + dblk * 16 + hh * 8);

    f32x16 o0 = zero16(), o1 = zero16();
    float m_run = -1e30f, l_run = 0.f;

    const int nt = 4 * qt + 4;
    const int ntw = (qwmin + 31) / 64 + 1;

    // prologue: stage tile 0 into buf 0
    gload_lds16(Kgb + (size_t)srow * 4096 + (sb ^ ssw), lds + w * 512);
    gload_lds16(Vgb + (size_t)srow * 4096 + (sb ^ ssw), lds + 4096 + w * 512);
    __syncthreads();

    int cur = 0;
    for (int t = 0; t < nt; ++t) {
      // stage next tile into the other buffer (flies during compute)
      if (t + 1 < nt) {
        const int k0n = (t + 1) * 64;
        short* kb = lds + (cur ^ 1) * 8192 + w * 512;
        gload_lds16(Kgb + (size_t)(k0n + srow) * 4096 + (sb ^ ssw), kb);
        gload_lds16(Vgb + (size_t)srow * 4096 + (size_t)k0n * 2 + (sb ^ ssw), kb + 4096);
      }

      if (t < ntw) {
        const int k0 = t * 64;
        const char* Kc = (const char*)lds + cur * 16384;
        const char* Vc = Kc + 8192;
        const int xs = (l31 & 7) << 4;

        // S^T = K Q^T over 4 d-blocks, 2 kv-subtiles
        f32x16 st0 = zero16(), st1 = zero16();
#pragma unroll
        for (int dblk = 0; dblk < 4; ++dblk) {
          const int off = (dblk * 32 + hh * 16) ^ xs;
          const short8_t kf0 = *(const short8_t*)(Kc + l31 * 128 + off);
          const short8_t kf1 = *(const short8_t*)(Kc + (32 + l31) * 128 + off);
          st0 = __builtin_amdgcn_mfma_f32_32x32x16_bf16(kf0, qf[dblk], st0, 0, 0, 0);
          st1 = __builtin_amdgcn_mfma_f32_32x32x16_bf16(kf1, qf[dblk], st1, 0, 0, 0);
        }

        // causal mask (diagonal tiles only)
        if (k0 + 63 > qwmin) {
#pragma unroll
          for (int r = 0; r < 16; ++r) {
            const int kvr = k0 + ((r & 3) + 8 * (r >> 2) + 4 * hh);
            if (kvr > qg) st0[r] = -1e30f;
            if (kvr + 32 > qg) st1[r] = -1e30f;
          }
        }

        // online softmax (exp2 domain; scale folded into Q)
        float mv = -1e30f;
#pragma unroll
        for (int r = 0; r < 16; ++r) mv = fmaxf(mv, fmaxf(st0[r], st1[r]));
        mv = fmaxf(mv, __shfl_xor(mv, 32));
        const float mnew = fmaxf(m_run, mv);
        const float alpha = exp2f(m_run - mnew);
        m_run = mnew;
        float sum = 0.f;
#pragma unroll
        for (int r = 0; r < 16; ++r) {
          st0[r] = exp2f(st0[r] - mnew);
          st1[r] = exp2f(st1[r] - mnew);
          sum += st0[r] + st1[r];
        }
        sum += __shfl_xor(sum, 32);
        l_run = l_run * alpha + sum;
        o0 = o0 * alpha;
        o1 = o1 * alpha;

        // P -> bf16 fragments in-register: cvt_pk + permlane32_swap
        uint pk_[16];
#pragma unroll
        for (int j = 0; j < 8; ++j) pk_[j] = cvt_pk_bf16(st0[2 * j], st0[2 * j + 1]);
#pragma unroll
        for (int j = 0; j < 8; ++j) pk_[8 + j] = cvt_pk_bf16(st1[2 * j], st1[2 * j + 1]);
        pl32swap(pk_[0], pk_[2]);  pl32swap(pk_[1], pk_[3]);
        pl32swap(pk_[4], pk_[6]);  pl32swap(pk_[5], pk_[7]);
        pl32swap(pk_[8], pk_[10]); pl32swap(pk_[9], pk_[11]);
        pl32swap(pk_[12], pk_[14]); pl32swap(pk_[13], pk_[15]);
        uint4_t paw[4];
#pragma unroll
        for (int f = 0; f < 4; ++f)
          paw[f] = (uint4_t){pk_[4 * f], pk_[4 * f + 1], pk_[4 * f + 2], pk_[4 * f + 3]};

        // O^T += V^T P^T  (A = V^T rows d, B = P^T col q -> output col=q, reg=d)
#pragma unroll
        for (int kb = 0; kb < 4; ++kb) {
          const short8_t pa = *(const short8_t*)&paw[kb];
          const int off = (kb * 32 + hh * 16) ^ xs;
          const short8_t vf0 = *(const short8_t*)(Vc + l31 * 128 + off);
          const short8_t vf1 = *(const short8_t*)(Vc + (32 + l31) * 128 + off);
          o0 = __builtin_amdgcn_mfma_f32_32x32x16_bf16(vf0, pa, o0, 0, 0, 0);
          o1 = __builtin_amdgcn_mfma_f32_32x32x16_bf16(vf1, pa, o1, 0, 0, 0);
        }
      }

      __syncthreads();
      cur ^= 1;
    }

    // epilogue: O^T (reg=d, lane=q) through swizzled per-wave LDS transpose -> coalesced stores
    {
      short* ow = lds + w * 2048;  // [32 q][64 d] bytes-swizzled
      const float inv = 1.0f / l_run;
#pragma unroll
      for (int r = 0; r < 16; ++r) {
        const int d = (r & 3) + 8 * (r >> 2) + 4 * hh;
        const int x = (l31 & 7) << 4;
        *(short*)((char*)ow + l31 * 128 + ((d * 2) ^ x)) = f2bf(o0[r] * inv);
        *(short*)((char*)ow + l31 * 128 + (((d + 32) * 2) ^ x)) = f2bf(o1[r] * inv);
      }
#pragma unroll
      for (int pz = 0; pz < 4; ++pz) {
        const int qloc = pz * 8 + (lane >> 3);
        const int sbyte = (lane & 7) * 16;
        const short8_t vv = *(const short8_t*)((char*)ow + qloc * 128 + (sbyte ^ ((qloc & 7) << 4)));
        *(short8_t*)(Og + ((size_t)(b * S_ + q0 + w * 32 + qloc)) * E_ + h * 64 + (lane & 7) * 8) = vv;
      }
    }
    __syncthreads();  // protect LDS before next phase's staging
  }
}

// ---------------- launch ----------------
extern "C" void kernel_launch(void* const* d_in, const int* in_sizes, int n_in,
                              void* d_out, int out_size, void* d_ws, size_t ws_size,
                              hipStream_t stream) {
  const float* X  = (const float*)d_in[0];
  const float* Wq = (const float*)d_in[1];
  const float* bq = (const float*)d_in[2];
  const float* Wk = (const float*)d_in[3];
  const float* bk = (const float*)d_in[4];
  const float* Wv = (const float*)d_in[5];
  const float* bv = (const float*)d_in[6];
  const float* Wo = (const float*)d_in[7];
  const float* bo = (const float*)d_in[8];

  const size_t NX = (size_t)B_ * S_ * E_;  // 8388608
  const size_t NW = (size_t)E_ * E_;       // 4194304

  short* ws = (short*)d_ws;
  short* Xb = ws;            // [B*S, E] bf16
  short* Wb = Xb + NX;       // 3*NW: Wq|Wk|Wv (later first NW reused for Wo)
  short* Kb = Wb + 3 * NW;   // [B*S, E]
  short* Vb = Kb + NX;       // V^T [b*E+n][S]
  short* Qb = (short*)d_out; // Q (scaled) parked in d_out (bf16, half of f32 buffer)
  short* Ab = Xb;            // attention output reuses X (dead after gemm_qkv)

  cast_bf16_kernel<<<2048, 256, 0, stream>>>(X, Xb, (int)(NX / 4));
  cast3_bf16<<<3072, 256, 0, stream>>>(Wq, Wk, Wv, Wb);

  gemm_qkv<<<dim3(3 * E_ / BN, B_ * S_ / BM), 256, 0, stream>>>(Xb, Wb, bq, bk, bv, Qb, Kb, Vb);

  cast_bf16_kernel<<<1024, 256, 0, stream>>>(Wo, Wb, (int)(NW / 4));

  attn_fwd<<<dim3(B_ * H_, 4), 512, 0, stream>>>(Qb, Kb, Vb, Ab);

  gemm_o<<<dim3(E_ / BN, B_ * S_ / BM), 256, 0, stream>>>(Ab, Wb, bo, (float*)d_out);
}

// Round 5
// 267.749 us; speedup vs baseline: 2.0873x; 1.0684x over previous
//
#include <hip/hip_runtime.h>
#include <hip/hip_bf16.h>

#define B_ 2
#define S_ 2048
#define E_ 2048
#define H_ 32
#define D_ 64
#define SCALE_L2E 0.18033688f  // 0.125 * log2(e)

typedef __attribute__((ext_vector_type(8))) short short8_t;
typedef __attribute__((ext_vector_type(4))) float float4_t;
typedef __attribute__((ext_vector_type(16))) float f32x16;
typedef unsigned int uint;
typedef __attribute__((ext_vector_type(4))) uint uint4_t;

__device__ __forceinline__ short f2bf(float f) {
  union { float f; unsigned u; } x; x.f = f;
  unsigned r = x.u + 0x7fffu + ((x.u >> 16) & 1u);
  return (short)(r >> 16);
}

__device__ __forceinline__ void gload_lds16(const void* g, void* l) {
  __builtin_amdgcn_global_load_lds((const __attribute__((address_space(1))) void*)g,
                                   (__attribute__((address_space(3))) void*)l, 16, 0, 0);
}

__device__ __forceinline__ uint cvt_pk_bf16(float lo, float hi) {
  uint r;
  asm volatile("v_cvt_pk_bf16_f32 %0, %1, %2" : "=v"(r) : "v"(lo), "v"(hi));
  return r;
}

__device__ __forceinline__ void pl32swap(uint& a, uint& b) {
  asm volatile("v_permlane32_swap_b32 %0, %1" : "+v"(a), "+v"(b));
}

__device__ __forceinline__ f32x16 zero16() {
  f32x16 v;
#pragma unroll
  for (int i = 0; i < 16; ++i) v[i] = 0.f;
  return v;
}

// ---------------- casts ----------------
__global__ void cast_bf16_kernel(const float* __restrict__ in, short* __restrict__ out, int n4) {
  const int stride = gridDim.x * blockDim.x;
  for (int j = blockIdx.x * blockDim.x + threadIdx.x; j < n4; j += stride) {
    const float4 v = ((const float4*)in)[j];
    short4 r;
    r.x = f2bf(v.x); r.y = f2bf(v.y); r.z = f2bf(v.z); r.w = f2bf(v.w);
    ((short4*)out)[j] = r;
  }
}

__global__ void cast3_bf16(const float* __restrict__ a, const float* __restrict__ b,
                           const float* __restrict__ c, short* __restrict__ out) {
  constexpr int n4 = (E_ * E_) / 4;  // 2^20
  const int stride = gridDim.x * blockDim.x;
  for (int j = blockIdx.x * blockDim.x + threadIdx.x; j < 3 * n4; j += stride) {
    const float* src = (j < n4) ? a : (j < 2 * n4 ? b : c);
    const int idx = j & (n4 - 1);
    const float4 v = ((const float4*)src)[idx];
    short4 r;
    r.x = f2bf(v.x); r.y = f2bf(v.y); r.z = f2bf(v.z); r.w = f2bf(v.w);
    ((short4*)out)[j] = r;
  }
}

// ---------------- fused QKV GEMM: 256x256 tile, BK=64, 8-phase counted-vmcnt ----------------
// C[m][n] = sum_k X[m][k] * W[n][k] + bias; W = [Wq;Wk;Wv] (6144 rows).
// seg 0: Q row-major scaled by SCALE_L2E. seg 1: K row-major. seg 2: V^T [b*E+n][S].
// LDS: A regions (d,ks) at (d*2+ks)*16384, B at 65536 + (d*2+ks)*16384 (each 256x32 bf16 = 16KB).
// Swizzle: within 64B rows, 16B slot ^= (row>>1)&3 (pre-swizzled global source; swizzled ds_read).

#define MFMA_WIN(CH)                                                                   \
  asm volatile("s_waitcnt lgkmcnt(0)" ::: "memory");                                   \
  __builtin_amdgcn_sched_barrier(0);                                                   \
  __builtin_amdgcn_s_setprio(1);                                                       \
  _Pragma("unroll")                                                                    \
  for (int i_ = 0; i_ < 8; ++i_) {                                                     \
    acc[i_][2*(CH)]   = __builtin_amdgcn_mfma_f32_16x16x32_bf16(a_[i_], b0, acc[i_][2*(CH)], 0, 0, 0);   \
    acc[i_][2*(CH)+1] = __builtin_amdgcn_mfma_f32_16x16x32_bf16(a_[i_], b1, acc[i_][2*(CH)+1], 0, 0, 0); \
  }                                                                                    \
  __builtin_amdgcn_s_setprio(0);                                                       \
  __builtin_amdgcn_s_barrier();

__global__ __launch_bounds__(512, 2) void gemm8_qkv(const short* __restrict__ A,
                                                    const short* __restrict__ Wt,
                                                    const float* __restrict__ bq,
                                                    const float* __restrict__ bk,
                                                    const float* __restrict__ bv,
                                                    short* __restrict__ Qb,
                                                    short* __restrict__ Kb,
                                                    short* __restrict__ Vb) {
  extern __shared__ __align__(16) char lds[];
  constexpr int K = E_, NT = K / 64;
  const int tid = threadIdx.x, w = tid >> 6, lane = tid & 63;
  const int wr = w >> 2, wc = w & 3;
  const int m0 = blockIdx.y * 256, n0 = blockIdx.x * 256;
  const int l15 = lane & 15, l4 = lane >> 4;

  // per-lane pre-swizzled global staging bases (2 row-sets of 128 rows each)
  const char* aB[2];
  const char* bB[2];
#pragma unroll
  for (int g = 0; g < 2; ++g) {
    const int r = g * 128 + w * 16 + (lane >> 2);
    const int sw = ((lane & 3) ^ ((r >> 1) & 3)) * 16;
    aB[g] = (const char*)A + (size_t)(m0 + r) * (K * 2) + sw;
    bB[g] = (const char*)Wt + (size_t)(n0 + r) * (K * 2) + sw;
  }
  const int ldsw = w * 1024;

  // stage one 16KB region (2 gload_lds per wave); roff = region byte offset
  auto stage = [&](const char* const* base, int roff, int kt, int kh) {
    const int koff = kt * 128 + kh * 64;
#pragma unroll
    for (int g = 0; g < 2; ++g)
      gload_lds16(base[g] + koff, lds + roff + g * 8192 + ldsw);
  };

  auto ldA = [&](int dd, int ks, int i) {
    const int lr = wr * 128 + i * 16 + l15;
    return *(const short8_t*)(lds + (dd * 2 + ks) * 16384 + lr * 64 +
                              ((l4 * 16) ^ (((lr >> 1) & 3) << 4)));
  };
  auto ldB = [&](int dd, int ks, int j) {
    const int lc = wc * 64 + j * 16 + l15;
    return *(const short8_t*)(lds + 65536 + (dd * 2 + ks) * 16384 + lc * 64 +
                              ((l4 * 16) ^ (((lc >> 1) & 3) << 4)));
  };

  float4_t acc[8][4];
#pragma unroll
  for (int i = 0; i < 8; ++i)
#pragma unroll
    for (int j = 0; j < 4; ++j) acc[i][j] = (float4_t){0.f, 0.f, 0.f, 0.f};

  // prologue: A(0,k0) B(0,k0) A(0,k1) B(0,k1) A(1,k0) B(1,k0); wait first 2 regions
  stage(aB, 0 * 16384, 0, 0);
  stage(bB, 65536 + 0 * 16384, 0, 0);
  stage(aB, 1 * 16384, 0, 1);
  stage(bB, 65536 + 1 * 16384, 0, 1);
  stage(aB, 2 * 16384, 1, 0);
  stage(bB, 65536 + 2 * 16384, 1, 0);
  asm volatile("s_waitcnt vmcnt(8)" ::: "memory");
  __builtin_amdgcn_s_barrier();

  short8_t a_[8], b0, b1;
  for (int t = 0; t < NT; ++t) {
    const int d = t & 1;
    // ---- phase 1: ks=0, col-frags 0-1; stage A(t+1,k1) -> other buf
    asm volatile("" ::: "memory");
#pragma unroll
    for (int i = 0; i < 8; ++i) a_[i] = ldA(d, 0, i);
    b0 = ldB(d, 0, 0);
    b1 = ldB(d, 0, 1);
    if (t + 1 < NT) stage(aB, ((d ^ 1) * 2 + 1) * 16384, t + 1, 1);
    __builtin_amdgcn_s_barrier();
    MFMA_WIN(0)
    // ---- phase 2: ks=0, col-frags 2-3; stage B(t+1,k1); vmcnt(8)
    asm volatile("" ::: "memory");
    b0 = ldB(d, 0, 2);
    b1 = ldB(d, 0, 3);
    if (t + 1 < NT) stage(bB, 65536 + ((d ^ 1) * 2 + 1) * 16384, t + 1, 1);
    if (t < NT - 1) { asm volatile("s_waitcnt vmcnt(8)" ::: "memory"); }
    else           { asm volatile("s_waitcnt vmcnt(0)" ::: "memory"); }
    __builtin_amdgcn_s_barrier();
    MFMA_WIN(1)
    // ---- phase 3: ks=1, col-frags 0-1; stage A(t+2,k0) -> just-freed region of current buf
    asm volatile("" ::: "memory");
#pragma unroll
    for (int i = 0; i < 8; ++i) a_[i] = ldA(d, 1, i);
    b0 = ldB(d, 1, 0);
    b1 = ldB(d, 1, 1);
    if (t + 2 < NT) stage(aB, (d * 2 + 0) * 16384, t + 2, 0);
    __builtin_amdgcn_s_barrier();
    MFMA_WIN(0)
    // ---- phase 4: ks=1, col-frags 2-3; stage B(t+2,k0); vmcnt(8)
    asm volatile("" ::: "memory");
    b0 = ldB(d, 1, 2);
    b1 = ldB(d, 1, 3);
    if (t + 2 < NT) stage(bB, 65536 + (d * 2 + 0) * 16384, t + 2, 0);
    if (t < NT - 1) { asm volatile("s_waitcnt vmcnt(8)" ::: "memory"); }
    else           { asm volatile("s_waitcnt vmcnt(0)" ::: "memory"); }
    __builtin_amdgcn_s_barrier();
    MFMA_WIN(1)
  }

  // ---------------- epilogue ----------------
  const int seg = n0 >> 11;  // 0=Q, 1=K, 2=V
  const int ncol = n0 & 2047;
  const int rg = l4 * 4;
  if (seg == 2) {
    // V^T: per-wave 64x64 transposes through swizzled LDS scratch (staging LDS is drained)
    char* qt = lds + w * 8192;
    const int b = m0 >> 11;
    const int mloc = m0 & (S_ - 1);
#pragma unroll
    for (int sb = 0; sb < 2; ++sb) {
      asm volatile("" ::: "memory");
#pragma unroll
      for (int j = 0; j < 4; ++j) {
        const float bvv = bv[ncol + wc * 64 + j * 16 + l15];
        const int nl = j * 16 + l15;
#pragma unroll
        for (int i = 0; i < 4; ++i) {
          short4 v;
          v.x = f2bf(acc[sb * 4 + i][j][0] + bvv);
          v.y = f2bf(acc[sb * 4 + i][j][1] + bvv);
          v.z = f2bf(acc[sb * 4 + i][j][2] + bvv);
          v.w = f2bf(acc[sb * 4 + i][j][3] + bvv);
          *(short4*)(qt + nl * 128 + (((i * 16 + rg) * 2) ^ ((nl & 7) << 4))) = v;
        }
      }
      asm volatile("s_waitcnt lgkmcnt(0)" ::: "memory");
      __builtin_amdgcn_sched_barrier(0);
#pragma unroll
      for (int p = 0; p < 8; ++p) {
        const int rowd = p * 8 + (lane >> 3);
        const short8_t vv =
            *(const short8_t*)(qt + rowd * 128 + (((lane & 7) * 16) ^ ((rowd & 7) << 4)));
        *(short8_t*)(Vb + ((size_t)(b * E_ + ncol + wc * 64 + rowd)) * S_ + mloc + wr * 128 +
                     sb * 64 + (lane & 7) * 8) = vv;
      }
      asm volatile("s_waitcnt lgkmcnt(0)" ::: "memory");
      __builtin_amdgcn_sched_barrier(0);
    }
  } else {
    const float* bias = seg ? bk : bq;
    short* Out = seg ? Kb : Qb;
    const float sc = seg ? 1.0f : SCALE_L2E;
#pragma unroll
    for (int j = 0; j < 4; ++j) {
      const int col = ncol + wc * 64 + j * 16 + l15;
      const float bvv = bias[col];
#pragma unroll
      for (int i = 0; i < 8; ++i)
#pragma unroll
        for (int ii = 0; ii < 4; ++ii)
          Out[(size_t)(m0 + wr * 128 + i * 16 + rg + ii) * E_ + col] =
              f2bf((acc[i][j][ii] + bvv) * sc);
    }
  }
}

// ---------------- output-projection GEMM (m97 structure, f32 out) ----------------
#define BM 128
#define BN 128
#define BK 32

__global__ __launch_bounds__(256) void gemm_o(const short* __restrict__ A,
                                              const short* __restrict__ Wt,
                                              const float* __restrict__ bias,
                                              float* __restrict__ Cout) {
  __shared__ __align__(16) short smem[2 * BM * BK];
  short* As = smem;
  short* Bs = smem + BM * BK;
  const int K = E_, N = E_;
  const int tid = threadIdx.x;
  const int w = tid >> 6;
  const int lane = tid & 63;
  const int m0 = blockIdx.y * BM;
  const int n0 = blockIdx.x * BN;
  const int wr = w >> 1, wc = w & 1;
  const int r16 = lane & 15;
  const int c8 = (lane >> 4) * 8;

  const int srow = lane >> 2;
  const int scol = (lane & 3) * 8;
  const short* aG0 = A  + (size_t)(m0 + (w * 2 + 0) * 16 + srow) * K + scol;
  const short* aG1 = A  + (size_t)(m0 + (w * 2 + 1) * 16 + srow) * K + scol;
  const short* bG0 = Wt + (size_t)(n0 + (w * 2 + 0) * 16 + srow) * K + scol;
  const short* bG1 = Wt + (size_t)(n0 + (w * 2 + 1) * 16 + srow) * K + scol;
  short* aL0 = As + (w * 2 + 0) * 512;
  short* aL1 = As + (w * 2 + 1) * 512;
  short* bL0 = Bs + (w * 2 + 0) * 512;
  short* bL1 = Bs + (w * 2 + 1) * 512;

  float4_t acc[4][4];
#pragma unroll
  for (int mi = 0; mi < 4; ++mi)
#pragma unroll
    for (int ni = 0; ni < 4; ++ni) acc[mi][ni] = (float4_t){0.f, 0.f, 0.f, 0.f};

  for (int kt = 0; kt < K; kt += BK) {
    __syncthreads();
    gload_lds16(aG0, aL0);
    gload_lds16(aG1, aL1);
    gload_lds16(bG0, bL0);
    gload_lds16(bG1, bL1);
    aG0 += BK; aG1 += BK; bG0 += BK; bG1 += BK;
    __syncthreads();
    short8_t af[4], bf[4];
#pragma unroll
    for (int i = 0; i < 4; ++i)
      af[i] = *(const short8_t*)(As + (wr * 64 + i * 16 + r16) * BK + c8);
#pragma unroll
    for (int i = 0; i < 4; ++i)
      bf[i] = *(const short8_t*)(Bs + (wc * 64 + i * 16 + r16) * BK + c8);
#pragma unroll
    for (int mi = 0; mi < 4; ++mi)
#pragma unroll
      for (int ni = 0; ni < 4; ++ni)
        acc[mi][ni] = __builtin_amdgcn_mfma_f32_16x16x32_bf16(af[mi], bf[ni], acc[mi][ni], 0, 0, 0);
  }

  const int rg = (lane >> 4) * 4;
  const int colbase = n0 + wc * 64;
  const int rowbase = m0 + wr * 64 + rg;
#pragma unroll
  for (int ni = 0; ni < 4; ++ni) {
    const int col = colbase + ni * 16 + r16;
    const float bvv = bias[col];
#pragma unroll
    for (int mi = 0; mi < 4; ++mi)
#pragma unroll
      for (int ii = 0; ii < 4; ++ii)
        Cout[(size_t)(rowbase + mi * 16 + ii) * N + col] = acc[mi][ni][ii] + bvv;
  }
}

// ---------------- causal flash attention (swapped 32x32, 8 waves) ----------------
__global__ __launch_bounds__(512, 2) void attn_fwd(const short* __restrict__ Qg,
                                                   const short* __restrict__ Kg,
                                                   const short* __restrict__ Vt,
                                                   short* __restrict__ Og) {
  __shared__ __align__(16) short lds[16384];  // 2 bufs x (K 8KB + V^T 8KB)
  const int tid = threadIdx.x, w = tid >> 6, lane = tid & 63;
  const int l31 = lane & 31, hh = lane >> 5;
  const int bh = blockIdx.x;
  const int b = bh >> 5, h = bh & 31;
  const int pq = blockIdx.y;  // 0..3

  const char* Kgb = (const char*)(Kg + (size_t)b * S_ * E_ + h * D_);
  const char* Vgb = (const char*)(Vt + (size_t)bh * 64 * S_);

  const int srow = w * 8 + (lane >> 3);       // 0..63
  const int sb = (lane & 7) * 16;
  const int ssw = (srow & 7) << 4;

#pragma unroll 1
  for (int ph = 0; ph < 2; ++ph) {
    const int qt = ph ? (7 - pq) : pq;
    const int q0 = qt * 256;
    const int qwmin = q0 + w * 32;
    const int qg = qwmin + l31;

    const short* qr = Qg + ((size_t)(b * S_ + qg)) * E_ + h * D_;
    short8_t qf[4];
#pragma unroll
    for (int dblk = 0; dblk < 4; ++dblk)
      qf[dblk] = *(const short8_t*)(qr + dblk * 16 + hh * 8);

    f32x16 o0 = zero16(), o1 = zero16();
    float m_run = -1e30f, l_run = 0.f;

    const int nt = 4 * qt + 4;
    const int ntw = (qwmin + 31) / 64 + 1;

    gload_lds16(Kgb + (size_t)srow * 4096 + (sb ^ ssw), lds + w * 512);
    gload_lds16(Vgb + (size_t)srow * 4096 + (sb ^ ssw), lds + 4096 + w * 512);
    __syncthreads();

    int cur = 0;
    for (int t = 0; t < nt; ++t) {
      if (t + 1 < nt) {
        const int k0n = (t + 1) * 64;
        short* kb = lds + (cur ^ 1) * 8192 + w * 512;
        gload_lds16(Kgb + (size_t)(k0n + srow) * 4096 + (sb ^ ssw), kb);
        gload_lds16(Vgb + (size_t)srow * 4096 + (size_t)k0n * 2 + (sb ^ ssw), kb + 4096);
      }

      if (t < ntw) {
        const int k0 = t * 64;
        const char* Kc = (const char*)lds + cur * 16384;
        const char* Vc = Kc + 8192;
        const int xs = (l31 & 7) << 4;

        f32x16 st0 = zero16(), st1 = zero16();
#pragma unroll
        for (int dblk = 0; dblk < 4; ++dblk) {
          const int off = (dblk * 32 + hh * 16) ^ xs;
          const short8_t kf0 = *(const short8_t*)(Kc + l31 * 128 + off);
          const short8_t kf1 = *(const short8_t*)(Kc + (32 + l31) * 128 + off);
          st0 = __builtin_amdgcn_mfma_f32_32x32x16_bf16(kf0, qf[dblk], st0, 0, 0, 0);
          st1 = __builtin_amdgcn_mfma_f32_32x32x16_bf16(kf1, qf[dblk], st1, 0, 0, 0);
        }

        if (k0 + 63 > qwmin) {
#pragma unroll
          for (int r = 0; r < 16; ++r) {
            const int kvr = k0 + ((r & 3) + 8 * (r >> 2) + 4 * hh);
            if (kvr > qg) st0[r] = -1e30f;
            if (kvr + 32 > qg) st1[r] = -1e30f;
          }
        }

        float mv = -1e30f;
#pragma unroll
        for (int r = 0; r < 16; ++r) mv = fmaxf(mv, fmaxf(st0[r], st1[r]));
        mv = fmaxf(mv, __shfl_xor(mv, 32));
        const float mnew = fmaxf(m_run, mv);
        const float alpha = exp2f(m_run - mnew);
        m_run = mnew;
        float sum = 0.f;
#pragma unroll
        for (int r = 0; r < 16; ++r) {
          st0[r] = exp2f(st0[r] - mnew);
          st1[r] = exp2f(st1[r] - mnew);
          sum += st0[r] + st1[r];
        }
        sum += __shfl_xor(sum, 32);
        l_run = l_run * alpha + sum;
        o0 = o0 * alpha;
        o1 = o1 * alpha;

        uint pk_[16];
#pragma unroll
        for (int j = 0; j < 8; ++j) pk_[j] = cvt_pk_bf16(st0[2 * j], st0[2 * j + 1]);
#pragma unroll
        for (int j = 0; j < 8; ++j) pk_[8 + j] = cvt_pk_bf16(st1[2 * j], st1[2 * j + 1]);
        pl32swap(pk_[0], pk_[2]);  pl32swap(pk_[1], pk_[3]);
        pl32swap(pk_[4], pk_[6]);  pl32swap(pk_[5], pk_[7]);
        pl32swap(pk_[8], pk_[10]); pl32swap(pk_[9], pk_[11]);
        pl32swap(pk_[12], pk_[14]); pl32swap(pk_[13], pk_[15]);
        uint4_t paw[4];
#pragma unroll
        for (int f = 0; f < 4; ++f)
          paw[f] = (uint4_t){pk_[4 * f], pk_[4 * f + 1], pk_[4 * f + 2], pk_[4 * f + 3]};

#pragma unroll
        for (int kb = 0; kb < 4; ++kb) {
          const short8_t pa = *(const short8_t*)&paw[kb];
          const int off = (kb * 32 + hh * 16) ^ xs;
          const short8_t vf0 = *(const short8_t*)(Vc + l31 * 128 + off);
          const short8_t vf1 = *(const short8_t*)(Vc + (32 + l31) * 128 + off);
          o0 = __builtin_amdgcn_mfma_f32_32x32x16_bf16(vf0, pa, o0, 0, 0, 0);
          o1 = __builtin_amdgcn_mfma_f32_32x32x16_bf16(vf1, pa, o1, 0, 0, 0);
        }
      }

      __syncthreads();
      cur ^= 1;
    }

    {
      short* ow = lds + w * 2048;
      const float inv = 1.0f / l_run;
#pragma unroll
      for (int r = 0; r < 16; ++r) {
        const int d = (r & 3) + 8 * (r >> 2) + 4 * hh;
        const int x = (l31 & 7) << 4;
        *(short*)((char*)ow + l31 * 128 + ((d * 2) ^ x)) = f2bf(o0[r] * inv);
        *(short*)((char*)ow + l31 * 128 + (((d + 32) * 2) ^ x)) = f2bf(o1[r] * inv);
      }
#pragma unroll
      for (int pz = 0; pz < 4; ++pz) {
        const int qloc = pz * 8 + (lane >> 3);
        const int sbyte = (lane & 7) * 16;
        const short8_t vv = *(const short8_t*)((char*)ow + qloc * 128 + (sbyte ^ ((qloc & 7) << 4)));
        *(short8_t*)(Og + ((size_t)(b * S_ + q0 + w * 32 + qloc)) * E_ + h * 64 + (lane & 7) * 8) = vv;
      }
    }
    __syncthreads();
  }
}

// ---------------- launch ----------------
extern "C" void kernel_launch(void* const* d_in, const int* in_sizes, int n_in,
                              void* d_out, int out_size, void* d_ws, size_t ws_size,
                              hipStream_t stream) {
  const float* X  = (const float*)d_in[0];
  const float* Wq = (const float*)d_in[1];
  const float* bq = (const float*)d_in[2];
  const float* Wk = (const float*)d_in[3];
  const float* bk = (const float*)d_in[4];
  const float* Wv = (const float*)d_in[5];
  const float* bv = (const float*)d_in[6];
  const float* Wo = (const float*)d_in[7];
  const float* bo = (const float*)d_in[8];

  const size_t NX = (size_t)B_ * S_ * E_;  // 8388608
  const size_t NW = (size_t)E_ * E_;       // 4194304

  short* ws = (short*)d_ws;
  short* Xb = ws;            // [B*S, E] bf16
  short* Wb = Xb + NX;       // 3*NW: Wq|Wk|Wv (first NW reused for Wo later)
  short* Kb = Wb + 3 * NW;   // [B*S, E]
  short* Vb = Kb + NX;       // V^T [b*E+n][S]
  short* Qb = (short*)d_out; // Q (scaled) parked in d_out
  short* Ab = Xb;            // attention output reuses X

  (void)hipFuncSetAttribute((const void*)gemm8_qkv,
                            hipFuncAttributeMaxDynamicSharedMemorySize, 131072);

  cast_bf16_kernel<<<2048, 256, 0, stream>>>(X, Xb, (int)(NX / 4));
  cast3_bf16<<<3072, 256, 0, stream>>>(Wq, Wk, Wv, Wb);

  gemm8_qkv<<<dim3(3 * E_ / 256, B_ * S_ / 256), 512, 131072, stream>>>(Xb, Wb, bq, bk, bv,
                                                                        Qb, Kb, Vb);

  cast_bf16_kernel<<<1024, 256, 0, stream>>>(Wo, Wb, (int)(NW / 4));

  attn_fwd<<<dim3(B_ * H_, 4), 512, 0, stream>>>(Qb, Kb, Vb, Ab);

  gemm_o<<<dim3(E_ / BN, B_ * S_ / BM), 256, 0, stream>>>(Ab, Wb, bo, (float*)d_out);
}

// Round 6
// 254.911 us; speedup vs baseline: 2.1924x; 1.0504x over previous
//
#include <hip/hip_runtime.h>
#include <hip/hip_bf16.h>

#define B_ 2
#define S_ 2048
#define E_ 2048
#define H_ 32
#define D_ 64
#define SCALE_L2E 0.18033688f  // 0.125 * log2(e)

typedef __attribute__((ext_vector_type(8))) short short8_t;
typedef __attribute__((ext_vector_type(4))) float float4_t;
typedef __attribute__((ext_vector_type(16))) float f32x16;
typedef unsigned int uint;
typedef __attribute__((ext_vector_type(4))) uint uint4_t;

__device__ __forceinline__ short f2bf(float f) {
  union { float f; unsigned u; } x; x.f = f;
  unsigned r = x.u + 0x7fffu + ((x.u >> 16) & 1u);
  return (short)(r >> 16);
}

__device__ __forceinline__ void gload_lds16(const void* g, void* l) {
  __builtin_amdgcn_global_load_lds((const __attribute__((address_space(1))) void*)g,
                                   (__attribute__((address_space(3))) void*)l, 16, 0, 0);
}

__device__ __forceinline__ uint cvt_pk_bf16(float lo, float hi) {
  uint r;
  asm volatile("v_cvt_pk_bf16_f32 %0, %1, %2" : "=v"(r) : "v"(lo), "v"(hi));
  return r;
}

__device__ __forceinline__ void pl32swap(uint& a, uint& b) {
  asm volatile("v_permlane32_swap_b32 %0, %1" : "+v"(a), "+v"(b));
}

__device__ __forceinline__ f32x16 zero16() {
  f32x16 v;
#pragma unroll
  for (int i = 0; i < 16; ++i) v[i] = 0.f;
  return v;
}

// ---------------- casts ----------------
__global__ void cast_bf16_kernel(const float* __restrict__ in, short* __restrict__ out, int n4) {
  const int stride = gridDim.x * blockDim.x;
  for (int j = blockIdx.x * blockDim.x + threadIdx.x; j < n4; j += stride) {
    const float4 v = ((const float4*)in)[j];
    short4 r;
    r.x = f2bf(v.x); r.y = f2bf(v.y); r.z = f2bf(v.z); r.w = f2bf(v.w);
    ((short4*)out)[j] = r;
  }
}

__global__ void cast3_bf16(const float* __restrict__ a, const float* __restrict__ b,
                           const float* __restrict__ c, short* __restrict__ out) {
  constexpr int n4 = (E_ * E_) / 4;  // 2^20
  const int stride = gridDim.x * blockDim.x;
  for (int j = blockIdx.x * blockDim.x + threadIdx.x; j < 3 * n4; j += stride) {
    const float* src = (j < n4) ? a : (j < 2 * n4 ? b : c);
    const int idx = j & (n4 - 1);
    const float4 v = ((const float4*)src)[idx];
    short4 r;
    r.x = f2bf(v.x); r.y = f2bf(v.y); r.z = f2bf(v.z); r.w = f2bf(v.w);
    ((short4*)out)[j] = r;
  }
}

// ---------------- 128x256 / BK=64 8-wave counted-vmcnt GEMM ----------------
// C[m][n] = sum_k A[m][k] * W[n][k] + bias.
// MODE 0: QKV fat output (W = [Wq;Wk;Wv], seg by n0: Q scaled bf16 / K bf16 / V^T).
// MODE 1: f32 row-major out (bias = bq param, out = Fout).
// LDS (96KB): A regions (buf,ks) at (buf*2+ks)*8192; B at 32768 + (buf*2+ks)*16384.
// Swizzle: 64B rows, 16B slot ^= (row>>1)&3; pre-swizzled global source, swizzled read.
template <int MODE>
__global__ __launch_bounds__(512, 2) void gemm8(const short* __restrict__ A,
                                                const short* __restrict__ Wt,
                                                const float* __restrict__ bq,
                                                const float* __restrict__ bk,
                                                const float* __restrict__ bv,
                                                short* __restrict__ Qb,
                                                short* __restrict__ Kb,
                                                short* __restrict__ Vb,
                                                float* __restrict__ Fout) {
  extern __shared__ __align__(16) char lds[];
  constexpr int K = E_, NT = K / 64;
  const int tid = threadIdx.x, w = tid >> 6, lane = tid & 63;
  const int wr = w >> 2, wc = w & 3;  // 2 (m) x 4 (n) waves
  const int m0 = blockIdx.y * 128, n0 = blockIdx.x * 256;
  const int l15 = lane & 15, l4 = lane >> 4;

  // per-lane pre-swizzled staging bases
  const int sr = lane >> 2;     // 0..15
  const int ss = lane & 3;      // 16B slot
  const char* aBase;
  const char* bBase0;
  const char* bBase1;
  {
    const int ra = w * 16 + sr;
    aBase = (const char*)A + (size_t)(m0 + ra) * (K * 2) + ((ss ^ ((ra >> 1) & 3)) * 16);
    const int rb0 = 0 * 128 + w * 16 + sr;
    bBase0 = (const char*)Wt + (size_t)(n0 + rb0) * (K * 2) + ((ss ^ ((rb0 >> 1) & 3)) * 16);
    const int rb1 = 1 * 128 + w * 16 + sr;
    bBase1 = (const char*)Wt + (size_t)(n0 + rb1) * (K * 2) + ((ss ^ ((rb1 >> 1) & 3)) * 16);
  }

  auto stageA = [&](int dbuf, int ks, int kt) {
    gload_lds16(aBase + kt * 128 + ks * 64, lds + (dbuf * 2 + ks) * 8192 + w * 1024);
  };
  auto stageB = [&](int dbuf, int ks, int kt) {
    char* base = lds + 32768 + (dbuf * 2 + ks) * 16384 + w * 1024;
    gload_lds16(bBase0 + kt * 128 + ks * 64, base);
    gload_lds16(bBase1 + kt * 128 + ks * 64, base + 8192);
  };
  auto ldA = [&](int dbuf, int ks, int i) {
    const int lr = wr * 64 + i * 16 + l15;
    return *(const short8_t*)(lds + (dbuf * 2 + ks) * 8192 + lr * 64 +
                              ((l4 * 16) ^ (((lr >> 1) & 3) << 4)));
  };
  auto ldB = [&](int dbuf, int ks, int j) {
    const int lc = wc * 64 + j * 16 + l15;
    return *(const short8_t*)(lds + 32768 + (dbuf * 2 + ks) * 16384 + lc * 64 +
                              ((l4 * 16) ^ (((lc >> 1) & 3) << 4)));
  };

  float4_t acc[4][4];
#pragma unroll
  for (int i = 0; i < 4; ++i)
#pragma unroll
    for (int j = 0; j < 4; ++j) acc[i][j] = (float4_t){0.f, 0.f, 0.f, 0.f};

  // prologue: stage tile 0 fully into buf 0 (6 instructions/wave)
  stageA(0, 0, 0);
  stageB(0, 0, 0);
  stageA(0, 1, 0);
  stageB(0, 1, 0);

  short8_t a_[4], b_[4];
  for (int t = 0; t < NT; ++t) {
    const int c = t & 1;
#pragma unroll
    for (int ks = 0; ks < 2; ++ks) {
      if (t + 1 < NT) {
        stageA(c ^ 1, ks, t + 1);
        stageB(c ^ 1, ks, t + 1);
        asm volatile("s_waitcnt vmcnt(6)" ::: "memory");
      } else if (ks == 0) {
        asm volatile("s_waitcnt vmcnt(3)" ::: "memory");
      } else {
        asm volatile("s_waitcnt vmcnt(0)" ::: "memory");
      }
      __builtin_amdgcn_s_barrier();
      asm volatile("" ::: "memory");  // keep ds_reads below the barrier
#pragma unroll
      for (int i = 0; i < 4; ++i) a_[i] = ldA(c, ks, i);
#pragma unroll
      for (int j = 0; j < 4; ++j) b_[j] = ldB(c, ks, j);
      asm volatile("s_waitcnt lgkmcnt(0)" ::: "memory");
      __builtin_amdgcn_sched_barrier(0);
      __builtin_amdgcn_s_setprio(1);
#pragma unroll
      for (int i = 0; i < 4; ++i)
#pragma unroll
        for (int j = 0; j < 4; ++j)
          acc[i][j] = __builtin_amdgcn_mfma_f32_16x16x32_bf16(a_[i], b_[j], acc[i][j], 0, 0, 0);
      __builtin_amdgcn_s_setprio(0);
    }
  }

  // ---------------- epilogue ----------------
  const int rg = l4 * 4;
  if (MODE == 1) {
#pragma unroll
    for (int j = 0; j < 4; ++j) {
      const int col = n0 + wc * 64 + j * 16 + l15;
      const float bvv = bq[col];
#pragma unroll
      for (int i = 0; i < 4; ++i)
#pragma unroll
        for (int ii = 0; ii < 4; ++ii)
          Fout[(size_t)(m0 + wr * 64 + i * 16 + rg + ii) * E_ + col] = acc[i][j][ii] + bvv;
    }
  } else {
    const int seg = n0 >> 11;  // 0=Q, 1=K, 2=V
    const int ncol = n0 & 2047;
    if (seg == 2) {
      // V^T: per-wave 64x64 transpose through swizzled LDS scratch
      __syncthreads();  // staging LDS fully drained & all reads done
      char* qt = lds + w * 8192;
      const int b = m0 >> 11;
      const int mloc = m0 & (S_ - 1);
#pragma unroll
      for (int j = 0; j < 4; ++j) {
        const float bvv = bv[ncol + wc * 64 + j * 16 + l15];
        const int nl = j * 16 + l15;
#pragma unroll
        for (int i = 0; i < 4; ++i) {
          short4 v;
          v.x = f2bf(acc[i][j][0] + bvv);
          v.y = f2bf(acc[i][j][1] + bvv);
          v.z = f2bf(acc[i][j][2] + bvv);
          v.w = f2bf(acc[i][j][3] + bvv);
          *(short4*)(qt + nl * 128 + (((i * 16 + rg) * 2) ^ ((nl & 7) << 4))) = v;
        }
      }
      asm volatile("s_waitcnt lgkmcnt(0)" ::: "memory");
      __builtin_amdgcn_sched_barrier(0);
#pragma unroll
      for (int p = 0; p < 8; ++p) {
        const int rowd = p * 8 + (lane >> 3);
        const short8_t vv =
            *(const short8_t*)(qt + rowd * 128 + (((lane & 7) * 16) ^ ((rowd & 7) << 4)));
        *(short8_t*)(Vb + ((size_t)(b * E_ + ncol + wc * 64 + rowd)) * S_ + mloc + wr * 64 +
                     (lane & 7) * 8) = vv;
      }
    } else {
      const float* bias = seg ? bk : bq;
      short* Out = seg ? Kb : Qb;
      const float sc = seg ? 1.0f : SCALE_L2E;
#pragma unroll
      for (int j = 0; j < 4; ++j) {
        const int col = ncol + wc * 64 + j * 16 + l15;
        const float bvv = bias[col];
#pragma unroll
        for (int i = 0; i < 4; ++i)
#pragma unroll
          for (int ii = 0; ii < 4; ++ii)
            Out[(size_t)(m0 + wr * 64 + i * 16 + rg + ii) * E_ + col] =
                f2bf((acc[i][j][ii] + bvv) * sc);
      }
    }
  }
}

// ---------------- causal flash attention (swapped 32x32, 8 waves) ----------------
__global__ __launch_bounds__(512, 2) void attn_fwd(const short* __restrict__ Qg,
                                                   const short* __restrict__ Kg,
                                                   const short* __restrict__ Vt,
                                                   short* __restrict__ Og) {
  __shared__ __align__(16) short lds[16384];  // 2 bufs x (K 8KB + V^T 8KB)
  const int tid = threadIdx.x, w = tid >> 6, lane = tid & 63;
  const int l31 = lane & 31, hh = lane >> 5;
  const int bh = blockIdx.x;
  const int b = bh >> 5, h = bh & 31;
  const int pq = blockIdx.y;  // 0..3

  const char* Kgb = (const char*)(Kg + (size_t)b * S_ * E_ + h * D_);
  const char* Vgb = (const char*)(Vt + (size_t)bh * 64 * S_);

  const int srow = w * 8 + (lane >> 3);       // 0..63
  const int sb = (lane & 7) * 16;
  const int ssw = (srow & 7) << 4;

#pragma unroll 1
  for (int ph = 0; ph < 2; ++ph) {
    const int qt = ph ? (7 - pq) : pq;
    const int q0 = qt * 256;
    const int qwmin = q0 + w * 32;
    const int qg = qwmin + l31;

    const short* qr = Qg + ((size_t)(b * S_ + qg)) * E_ + h * D_;
    short8_t qf[4];
#pragma unroll
    for (int dblk = 0; dblk < 4; ++dblk)
      qf[dblk] = *(const short8_t*)(qr + dblk * 16 + hh * 8);

    f32x16 o0 = zero16(), o1 = zero16();
    float m_run = -1e30f, l_run = 0.f;

    const int nt = 4 * qt + 4;
    const int ntw = (qwmin + 31) / 64 + 1;

    gload_lds16(Kgb + (size_t)srow * 4096 + (sb ^ ssw), lds + w * 512);
    gload_lds16(Vgb + (size_t)srow * 4096 + (sb ^ ssw), lds + 4096 + w * 512);
    __syncthreads();

    int cur = 0;
    for (int t = 0; t < nt; ++t) {
      if (t + 1 < nt) {
        const int k0n = (t + 1) * 64;
        short* kb = lds + (cur ^ 1) * 8192 + w * 512;
        gload_lds16(Kgb + (size_t)(k0n + srow) * 4096 + (sb ^ ssw), kb);
        gload_lds16(Vgb + (size_t)srow * 4096 + (size_t)k0n * 2 + (sb ^ ssw), kb + 4096);
      }

      if (t < ntw) {
        const int k0 = t * 64;
        const char* Kc = (const char*)lds + cur * 16384;
        const char* Vc = Kc + 8192;
        const int xs = (l31 & 7) << 4;

        f32x16 st0 = zero16(), st1 = zero16();
#pragma unroll
        for (int dblk = 0; dblk < 4; ++dblk) {
          const int off = (dblk * 32 + hh * 16) ^ xs;
          const short8_t kf0 = *(const short8_t*)(Kc + l31 * 128 + off);
          const short8_t kf1 = *(const short8_t*)(Kc + (32 + l31) * 128 + off);
          st0 = __builtin_amdgcn_mfma_f32_32x32x16_bf16(kf0, qf[dblk], st0, 0, 0, 0);
          st1 = __builtin_amdgcn_mfma_f32_32x32x16_bf16(kf1, qf[dblk], st1, 0, 0, 0);
        }

        if (k0 + 63 > qwmin) {
#pragma unroll
          for (int r = 0; r < 16; ++r) {
            const int kvr = k0 + ((r & 3) + 8 * (r >> 2) + 4 * hh);
            if (kvr > qg) st0[r] = -1e30f;
            if (kvr + 32 > qg) st1[r] = -1e30f;
          }
        }

        float mv = -1e30f;
#pragma unroll
        for (int r = 0; r < 16; ++r) mv = fmaxf(mv, fmaxf(st0[r], st1[r]));
        mv = fmaxf(mv, __shfl_xor(mv, 32));
        const float mnew = fmaxf(m_run, mv);
        const float alpha = exp2f(m_run - mnew);
        m_run = mnew;
        float sum = 0.f;
#pragma unroll
        for (int r = 0; r < 16; ++r) {
          st0[r] = exp2f(st0[r] - mnew);
          st1[r] = exp2f(st1[r] - mnew);
          sum += st0[r] + st1[r];
        }
        sum += __shfl_xor(sum, 32);
        l_run = l_run * alpha + sum;
        o0 = o0 * alpha;
        o1 = o1 * alpha;

        uint pk_[16];
#pragma unroll
        for (int j = 0; j < 8; ++j) pk_[j] = cvt_pk_bf16(st0[2 * j], st0[2 * j + 1]);
#pragma unroll
        for (int j = 0; j < 8; ++j) pk_[8 + j] = cvt_pk_bf16(st1[2 * j], st1[2 * j + 1]);
        pl32swap(pk_[0], pk_[2]);  pl32swap(pk_[1], pk_[3]);
        pl32swap(pk_[4], pk_[6]);  pl32swap(pk_[5], pk_[7]);
        pl32swap(pk_[8], pk_[10]); pl32swap(pk_[9], pk_[11]);
        pl32swap(pk_[12], pk_[14]); pl32swap(pk_[13], pk_[15]);
        uint4_t paw[4];
#pragma unroll
        for (int f = 0; f < 4; ++f)
          paw[f] = (uint4_t){pk_[4 * f], pk_[4 * f + 1], pk_[4 * f + 2], pk_[4 * f + 3]};

#pragma unroll
        for (int kb = 0; kb < 4; ++kb) {
          const short8_t pa = *(const short8_t*)&paw[kb];
          const int off = (kb * 32 + hh * 16) ^ xs;
          const short8_t vf0 = *(const short8_t*)(Vc + l31 * 128 + off);
          const short8_t vf1 = *(const short8_t*)(Vc + (32 + l31) * 128 + off);
          o0 = __builtin_amdgcn_mfma_f32_32x32x16_bf16(vf0, pa, o0, 0, 0, 0);
          o1 = __builtin_amdgcn_mfma_f32_32x32x16_bf16(vf1, pa, o1, 0, 0, 0);
        }
      }

      __syncthreads();
      cur ^= 1;
    }

    {
      short* ow = lds + w * 2048;
      const float inv = 1.0f / l_run;
#pragma unroll
      for (int r = 0; r < 16; ++r) {
        const int d = (r & 3) + 8 * (r >> 2) + 4 * hh;
        const int x = (l31 & 7) << 4;
        *(short*)((char*)ow + l31 * 128 + ((d * 2) ^ x)) = f2bf(o0[r] * inv);
        *(short*)((char*)ow + l31 * 128 + (((d + 32) * 2) ^ x)) = f2bf(o1[r] * inv);
      }
#pragma unroll
      for (int pz = 0; pz < 4; ++pz) {
        const int qloc = pz * 8 + (lane >> 3);
        const int sbyte = (lane & 7) * 16;
        const short8_t vv = *(const short8_t*)((char*)ow + qloc * 128 + (sbyte ^ ((qloc & 7) << 4)));
        *(short8_t*)(Og + ((size_t)(b * S_ + q0 + w * 32 + qloc)) * E_ + h * 64 + (lane & 7) * 8) = vv;
      }
    }
    __syncthreads();
  }
}

// ---------------- launch ----------------
extern "C" void kernel_launch(void* const* d_in, const int* in_sizes, int n_in,
                              void* d_out, int out_size, void* d_ws, size_t ws_size,
                              hipStream_t stream) {
  const float* X  = (const float*)d_in[0];
  const float* Wq = (const float*)d_in[1];
  const float* bq = (const float*)d_in[2];
  const float* Wk = (const float*)d_in[3];
  const float* bk = (const float*)d_in[4];
  const float* Wv = (const float*)d_in[5];
  const float* bv = (const float*)d_in[6];
  const float* Wo = (const float*)d_in[7];
  const float* bo = (const float*)d_in[8];

  const size_t NX = (size_t)B_ * S_ * E_;  // 8388608
  const size_t NW = (size_t)E_ * E_;       // 4194304

  short* ws = (short*)d_ws;
  short* Xb = ws;            // [B*S, E] bf16
  short* Wb = Xb + NX;       // 3*NW: Wq|Wk|Wv (first NW reused for Wo later)
  short* Kb = Wb + 3 * NW;   // [B*S, E]
  short* Vb = Kb + NX;       // V^T [b*E+n][S]
  short* Qb = (short*)d_out; // Q (scaled) parked in d_out
  short* Ab = Xb;            // attention output reuses X

  (void)hipFuncSetAttribute((const void*)gemm8<0>,
                            hipFuncAttributeMaxDynamicSharedMemorySize, 98304);
  (void)hipFuncSetAttribute((const void*)gemm8<1>,
                            hipFuncAttributeMaxDynamicSharedMemorySize, 98304);

  cast_bf16_kernel<<<2048, 256, 0, stream>>>(X, Xb, (int)(NX / 4));
  cast3_bf16<<<3072, 256, 0, stream>>>(Wq, Wk, Wv, Wb);

  gemm8<0><<<dim3(3 * E_ / 256, B_ * S_ / 128), 512, 98304, stream>>>(Xb, Wb, bq, bk, bv,
                                                                      Qb, Kb, Vb, nullptr);

  cast_bf16_kernel<<<1024, 256, 0, stream>>>(Wo, Wb, (int)(NW / 4));

  attn_fwd<<<dim3(B_ * H_, 4), 512, 0, stream>>>(Qb, Kb, Vb, Ab);

  gemm8<1><<<dim3(E_ / 256, B_ * S_ / 128), 512, 98304, stream>>>(Ab, Wb, bo, nullptr, nullptr,
                                                                  nullptr, nullptr, nullptr,
                                                                  (float*)d_out);
}

// Round 8
// 251.240 us; speedup vs baseline: 2.2245x; 1.0146x over previous
//
#include <hip/hip_runtime.h>
#include <hip/hip_bf16.h>

#define B_ 2
#define S_ 2048
#define E_ 2048
#define H_ 32
#define D_ 64
#define SCALE_L2E 0.18033688f  // 0.125 * log2(e)

typedef __attribute__((ext_vector_type(8))) short short8_t;
typedef __attribute__((ext_vector_type(4))) float float4_t;
typedef __attribute__((ext_vector_type(16))) float f32x16;
typedef unsigned int uint;
typedef __attribute__((ext_vector_type(4))) uint uint4_t;

__device__ __forceinline__ short f2bf(float f) {
  union { float f; unsigned u; } x; x.f = f;
  unsigned r = x.u + 0x7fffu + ((x.u >> 16) & 1u);
  return (short)(r >> 16);
}

__device__ __forceinline__ void gload_lds16(const void* g, void* l) {
  __builtin_amdgcn_global_load_lds((const __attribute__((address_space(1))) void*)g,
                                   (__attribute__((address_space(3))) void*)l, 16, 0, 0);
}

__device__ __forceinline__ uint cvt_pk_bf16(float lo, float hi) {
  uint r;
  asm volatile("v_cvt_pk_bf16_f32 %0, %1, %2" : "=v"(r) : "v"(lo), "v"(hi));
  return r;
}

__device__ __forceinline__ void pl32swap(uint& a, uint& b) {
  asm volatile("v_permlane32_swap_b32 %0, %1" : "+v"(a), "+v"(b));
}

__device__ __forceinline__ f32x16 zero16() {
  f32x16 v;
#pragma unroll
  for (int i = 0; i < 16; ++i) v[i] = 0.f;
  return v;
}

// ---------------- casts ----------------
__global__ void cast_bf16_kernel(const float* __restrict__ in, short* __restrict__ out, int n4) {
  const int stride = gridDim.x * blockDim.x;
  for (int j = blockIdx.x * blockDim.x + threadIdx.x; j < n4; j += stride) {
    const float4 v = ((const float4*)in)[j];
    short4 r;
    r.x = f2bf(v.x); r.y = f2bf(v.y); r.z = f2bf(v.z); r.w = f2bf(v.w);
    ((short4*)out)[j] = r;
  }
}

__global__ void cast3_bf16(const float* __restrict__ a, const float* __restrict__ b,
                           const float* __restrict__ c, short* __restrict__ out) {
  constexpr int n4 = (E_ * E_) / 4;  // 2^20
  const int stride = gridDim.x * blockDim.x;
  for (int j = blockIdx.x * blockDim.x + threadIdx.x; j < 3 * n4; j += stride) {
    const float* src = (j < n4) ? a : (j < 2 * n4 ? b : c);
    const int idx = j & (n4 - 1);
    const float4 v = ((const float4*)src)[idx];
    short4 r;
    r.x = f2bf(v.x); r.y = f2bf(v.y); r.z = f2bf(v.z); r.w = f2bf(v.w);
    ((short4*)out)[j] = r;
  }
}

// ---------------- QKV GEMM: 128x384 tile, BK=64, 8 waves (2x4, per-wave 64x96) ----------------
// C[m][n] = sum_k X[m][k] * W[n][k] + bias; W = [Wq;Wk;Wv] rows (6144).
// Grid 16x32 = 512 blocks = 2.0 rounds of 256 CUs.
// LDS 128KB: A regions (buf,ks) at (buf*2+ks)*8192 (128x32 bf16 = 8KB);
//            B regions at 32768 + (buf*2+ks)*24576 (384x32 bf16 = 24KB).
// Swizzle: 64B rows, 16B slot ^= (row>>1)&3; pre-swizzled global source, swizzled ds_read.
// Epilogue per-16-col strip (tiles straddle the Q/K/V 2048-boundaries; strips never do).
__global__ __launch_bounds__(512, 2) void gemm384_qkv(const short* __restrict__ A,
                                                      const short* __restrict__ Wt,
                                                      const float* __restrict__ bq,
                                                      const float* __restrict__ bk,
                                                      const float* __restrict__ bv,
                                                      short* __restrict__ Qb,
                                                      short* __restrict__ Kb,
                                                      short* __restrict__ Vb) {
  extern __shared__ __align__(16) char lds[];
  constexpr int K = E_, NT = K / 64;
  const int tid = threadIdx.x, w = tid >> 6, lane = tid & 63;
  const int wr = w >> 2, wc = w & 3;  // 2 (m) x 4 (n)
  const int m0 = blockIdx.y * 128, n0 = blockIdx.x * 384;
  const int l15 = lane & 15, l4 = lane >> 4;

  // per-lane pre-swizzled staging bases
  const int sr = lane >> 2;  // 0..15
  const int ss = lane & 3;   // 16B slot
  const char* aBase;
  const char* bBase[3];
  {
    const int ra = w * 16 + sr;
    aBase = (const char*)A + (size_t)(m0 + ra) * (K * 2) + ((ss ^ ((ra >> 1) & 3)) * 16);
#pragma unroll
    for (int g = 0; g < 3; ++g) {
      const int rb = g * 128 + w * 16 + sr;
      bBase[g] = (const char*)Wt + (size_t)(n0 + rb) * (K * 2) + ((ss ^ ((rb >> 1) & 3)) * 16);
    }
  }

  auto stageA = [&](int buf, int ks, int kt) {
    gload_lds16(aBase + kt * 128 + ks * 64, lds + (buf * 2 + ks) * 8192 + w * 1024);
  };
  auto stageB = [&](int buf, int ks, int kt) {
    char* base = lds + 32768 + (buf * 2 + ks) * 24576 + w * 1024;
#pragma unroll
    for (int g = 0; g < 3; ++g)
      gload_lds16(bBase[g] + kt * 128 + ks * 64, base + g * 8192);
  };
  auto ldA = [&](int buf, int ks, int i) {
    const int lr = wr * 64 + i * 16 + l15;
    return *(const short8_t*)(lds + (buf * 2 + ks) * 8192 + lr * 64 +
                              ((l4 * 16) ^ (((lr >> 1) & 3) << 4)));
  };
  auto ldB = [&](int buf, int ks, int j) {
    const int lc = wc * 96 + j * 16 + l15;
    return *(const short8_t*)(lds + 32768 + (buf * 2 + ks) * 24576 + lc * 64 +
                              ((l4 * 16) ^ (((lc >> 1) & 3) << 4)));
  };

  float4_t acc[4][6];
#pragma unroll
  for (int i = 0; i < 4; ++i)
#pragma unroll
    for (int j = 0; j < 6; ++j) acc[i][j] = (float4_t){0.f, 0.f, 0.f, 0.f};

  // prologue: tile 0 fully into buf 0 (8 instrs/wave)
  stageA(0, 0, 0);
  stageB(0, 0, 0);
  stageA(0, 1, 0);
  stageB(0, 1, 0);

  short8_t a_[4], b_[6];
  for (int t = 0; t < NT; ++t) {
    const int c = t & 1;
#pragma unroll
    for (int ks = 0; ks < 2; ++ks) {
      if (t + 1 < NT) {
        stageA(c ^ 1, ks, t + 1);
        stageB(c ^ 1, ks, t + 1);
        asm volatile("s_waitcnt vmcnt(8)" ::: "memory");
      } else if (ks == 0) {
        asm volatile("s_waitcnt vmcnt(4)" ::: "memory");
      } else {
        asm volatile("s_waitcnt vmcnt(0)" ::: "memory");
      }
      __builtin_amdgcn_s_barrier();
      asm volatile("" ::: "memory");  // keep ds_reads below the barrier
#pragma unroll
      for (int i = 0; i < 4; ++i) a_[i] = ldA(c, ks, i);
#pragma unroll
      for (int j = 0; j < 6; ++j) b_[j] = ldB(c, ks, j);
      asm volatile("s_waitcnt lgkmcnt(0)" ::: "memory");
      __builtin_amdgcn_sched_barrier(0);
      __builtin_amdgcn_s_setprio(1);
#pragma unroll
      for (int i = 0; i < 4; ++i)
#pragma unroll
        for (int j = 0; j < 6; ++j)
          acc[i][j] = __builtin_amdgcn_mfma_f32_16x16x32_bf16(a_[i], b_[j], acc[i][j], 0, 0, 0);
      __builtin_amdgcn_s_setprio(0);
    }
  }

  // ---------------- epilogue: per-16-col strips ----------------
  __syncthreads();  // staging LDS dead; per-wave scratch below
  const int rg = l4 * 4;
  const int b = m0 >> 11;
  const int mloc = m0 & (S_ - 1);
  char* scratch = lds + w * 2048;  // 16 rows (n) x 128B (m), XOR-swizzled
#pragma unroll
  for (int j = 0; j < 6; ++j) {
    const int gc0 = n0 + wc * 96 + j * 16;
    const int seg = gc0 >> 11;  // 0=Q, 1=K, 2=V
    const int ncol = gc0 & 2047;
    if (seg == 2) {
      // strip transpose: scratch[n=l15][m], m-granule b stored at b ^ ((n&7)<<4)
      const float bvv = bv[ncol + l15];
      asm volatile("" ::: "memory");
#pragma unroll
      for (int i = 0; i < 4; ++i) {
        short4 v;
        v.x = f2bf(acc[i][j][0] + bvv);
        v.y = f2bf(acc[i][j][1] + bvv);
        v.z = f2bf(acc[i][j][2] + bvv);
        v.w = f2bf(acc[i][j][3] + bvv);
        *(short4*)(scratch + l15 * 128 + (((i * 16 + rg) * 2) ^ ((l15 & 7) << 4))) = v;
      }
      asm volatile("s_waitcnt lgkmcnt(0)" ::: "memory");
      __builtin_amdgcn_sched_barrier(0);
      // readback: full 16 rows x 128B in two halves; un-swizzle -> linear m store
#pragma unroll
      for (int half = 0; half < 2; ++half) {
        const int n = (lane >> 3) + half * 8;   // 0..15
        const int mb = (lane & 7) * 16;         // linear m-byte 0..112
        const short8_t vv =
            *(const short8_t*)(scratch + n * 128 + (mb ^ ((n & 7) << 4)));
        *(short8_t*)(Vb + ((size_t)(b * E_ + ncol + n)) * S_ + mloc + wr * 64 + (mb >> 1)) = vv;
      }
      asm volatile("s_waitcnt lgkmcnt(0)" ::: "memory");
      __builtin_amdgcn_sched_barrier(0);
    } else {
      const float* bias = seg ? bk : bq;
      short* Out = seg ? Kb : Qb;
      const float sc = seg ? 1.0f : SCALE_L2E;
      const int col = ncol + l15;
      const float bvv = bias[col];
#pragma unroll
      for (int i = 0; i < 4; ++i)
#pragma unroll
        for (int ii = 0; ii < 4; ++ii)
          Out[(size_t)(m0 + wr * 64 + i * 16 + rg + ii) * E_ + col] =
              f2bf((acc[i][j][ii] + bvv) * sc);
    }
  }
}

// ---------------- output-projection GEMM: 128x256 / BK=64 8-wave counted-vmcnt, f32 out ----------------
__global__ __launch_bounds__(512, 2) void gemm_o8(const short* __restrict__ A,
                                                  const short* __restrict__ Wt,
                                                  const float* __restrict__ bias,
                                                  float* __restrict__ Fout) {
  extern __shared__ __align__(16) char lds[];
  constexpr int K = E_, NT = K / 64;
  const int tid = threadIdx.x, w = tid >> 6, lane = tid & 63;
  const int wr = w >> 2, wc = w & 3;
  const int m0 = blockIdx.y * 128, n0 = blockIdx.x * 256;
  const int l15 = lane & 15, l4 = lane >> 4;

  const int sr = lane >> 2;
  const int ss = lane & 3;
  const char* aBase;
  const char* bBase0;
  const char* bBase1;
  {
    const int ra = w * 16 + sr;
    aBase = (const char*)A + (size_t)(m0 + ra) * (K * 2) + ((ss ^ ((ra >> 1) & 3)) * 16);
    const int rb0 = w * 16 + sr;
    bBase0 = (const char*)Wt + (size_t)(n0 + rb0) * (K * 2) + ((ss ^ ((rb0 >> 1) & 3)) * 16);
    const int rb1 = 128 + w * 16 + sr;
    bBase1 = (const char*)Wt + (size_t)(n0 + rb1) * (K * 2) + ((ss ^ ((rb1 >> 1) & 3)) * 16);
  }

  auto stageA = [&](int dbuf, int ks, int kt) {
    gload_lds16(aBase + kt * 128 + ks * 64, lds + (dbuf * 2 + ks) * 8192 + w * 1024);
  };
  auto stageB = [&](int dbuf, int ks, int kt) {
    char* base = lds + 32768 + (dbuf * 2 + ks) * 16384 + w * 1024;
    gload_lds16(bBase0 + kt * 128 + ks * 64, base);
    gload_lds16(bBase1 + kt * 128 + ks * 64, base + 8192);
  };
  auto ldA = [&](int dbuf, int ks, int i) {
    const int lr = wr * 64 + i * 16 + l15;
    return *(const short8_t*)(lds + (dbuf * 2 + ks) * 8192 + lr * 64 +
                              ((l4 * 16) ^ (((lr >> 1) & 3) << 4)));
  };
  auto ldB = [&](int dbuf, int ks, int j) {
    const int lc = wc * 64 + j * 16 + l15;
    return *(const short8_t*)(lds + 32768 + (dbuf * 2 + ks) * 16384 + lc * 64 +
                              ((l4 * 16) ^ (((lc >> 1) & 3) << 4)));
  };

  float4_t acc[4][4];
#pragma unroll
  for (int i = 0; i < 4; ++i)
#pragma unroll
    for (int j = 0; j < 4; ++j) acc[i][j] = (float4_t){0.f, 0.f, 0.f, 0.f};

  stageA(0, 0, 0);
  stageB(0, 0, 0);
  stageA(0, 1, 0);
  stageB(0, 1, 0);

  short8_t a_[4], b_[4];
  for (int t = 0; t < NT; ++t) {
    const int c = t & 1;
#pragma unroll
    for (int ks = 0; ks < 2; ++ks) {
      if (t + 1 < NT) {
        stageA(c ^ 1, ks, t + 1);
        stageB(c ^ 1, ks, t + 1);
        asm volatile("s_waitcnt vmcnt(6)" ::: "memory");
      } else if (ks == 0) {
        asm volatile("s_waitcnt vmcnt(3)" ::: "memory");
      } else {
        asm volatile("s_waitcnt vmcnt(0)" ::: "memory");
      }
      __builtin_amdgcn_s_barrier();
      asm volatile("" ::: "memory");
#pragma unroll
      for (int i = 0; i < 4; ++i) a_[i] = ldA(c, ks, i);
#pragma unroll
      for (int j = 0; j < 4; ++j) b_[j] = ldB(c, ks, j);
      asm volatile("s_waitcnt lgkmcnt(0)" ::: "memory");
      __builtin_amdgcn_sched_barrier(0);
      __builtin_amdgcn_s_setprio(1);
#pragma unroll
      for (int i = 0; i < 4; ++i)
#pragma unroll
        for (int j = 0; j < 4; ++j)
          acc[i][j] = __builtin_amdgcn_mfma_f32_16x16x32_bf16(a_[i], b_[j], acc[i][j], 0, 0, 0);
      __builtin_amdgcn_s_setprio(0);
    }
  }

  const int rg = l4 * 4;
#pragma unroll
  for (int j = 0; j < 4; ++j) {
    const int col = n0 + wc * 64 + j * 16 + l15;
    const float bvv = bias[col];
#pragma unroll
    for (int i = 0; i < 4; ++i)
#pragma unroll
      for (int ii = 0; ii < 4; ++ii)
        Fout[(size_t)(m0 + wr * 64 + i * 16 + rg + ii) * E_ + col] = acc[i][j][ii] + bvv;
  }
}

// ---------------- causal flash attention (swapped 32x32, 8 waves) ----------------
__global__ __launch_bounds__(512, 2) void attn_fwd(const short* __restrict__ Qg,
                                                   const short* __restrict__ Kg,
                                                   const short* __restrict__ Vt,
                                                   short* __restrict__ Og) {
  __shared__ __align__(16) short lds[16384];  // 2 bufs x (K 8KB + V^T 8KB)
  const int tid = threadIdx.x, w = tid >> 6, lane = tid & 63;
  const int l31 = lane & 31, hh = lane >> 5;
  const int bh = blockIdx.x;
  const int b = bh >> 5, h = bh & 31;
  const int pq = blockIdx.y;  // 0..3

  const char* Kgb = (const char*)(Kg + (size_t)b * S_ * E_ + h * D_);
  const char* Vgb = (const char*)(Vt + (size_t)bh * 64 * S_);

  const int srow = w * 8 + (lane >> 3);       // 0..63
  const int sb = (lane & 7) * 16;
  const int ssw = (srow & 7) << 4;

#pragma unroll 1
  for (int ph = 0; ph < 2; ++ph) {
    const int qt = ph ? (7 - pq) : pq;
    const int q0 = qt * 256;
    const int qwmin = q0 + w * 32;
    const int qg = qwmin + l31;

    const short* qr = Qg + ((size_t)(b * S_ + qg)) * E_ + h * D_;
    short8_t qf[4];
#pragma unroll
    for (int dblk = 0; dblk < 4; ++dblk)
      qf[dblk] = *(const short8_t*)(qr + dblk * 16 + hh * 8);

    f32x16 o0 = zero16(), o1 = zero16();
    float m_run = -1e30f, l_run = 0.f;

    const int nt = 4 * qt + 4;
    const int ntw = (qwmin + 31) / 64 + 1;

    gload_lds16(Kgb + (size_t)srow * 4096 + (sb ^ ssw), lds + w * 512);
    gload_lds16(Vgb + (size_t)srow * 4096 + (sb ^ ssw), lds + 4096 + w * 512);
    __syncthreads();

    int cur = 0;
    for (int t = 0; t < nt; ++t) {
      if (t + 1 < nt) {
        const int k0n = (t + 1) * 64;
        short* kb = lds + (cur ^ 1) * 8192 + w * 512;
        gload_lds16(Kgb + (size_t)(k0n + srow) * 4096 + (sb ^ ssw), kb);
        gload_lds16(Vgb + (size_t)srow * 4096 + (size_t)k0n * 2 + (sb ^ ssw), kb + 4096);
      }

      if (t < ntw) {
        const int k0 = t * 64;
        const char* Kc = (const char*)lds + cur * 16384;
        const char* Vc = Kc + 8192;
        const int xs = (l31 & 7) << 4;

        f32x16 st0 = zero16(), st1 = zero16();
#pragma unroll
        for (int dblk = 0; dblk < 4; ++dblk) {
          const int off = (dblk * 32 + hh * 16) ^ xs;
          const short8_t kf0 = *(const short8_t*)(Kc + l31 * 128 + off);
          const short8_t kf1 = *(const short8_t*)(Kc + (32 + l31) * 128 + off);
          st0 = __builtin_amdgcn_mfma_f32_32x32x16_bf16(kf0, qf[dblk], st0, 0, 0, 0);
          st1 = __builtin_amdgcn_mfma_f32_32x32x16_bf16(kf1, qf[dblk], st1, 0, 0, 0);
        }

        if (k0 + 63 > qwmin) {
#pragma unroll
          for (int r = 0; r < 16; ++r) {
            const int kvr = k0 + ((r & 3) + 8 * (r >> 2) + 4 * hh);
            if (kvr > qg) st0[r] = -1e30f;
            if (kvr + 32 > qg) st1[r] = -1e30f;
          }
        }

        float mv = -1e30f;
#pragma unroll
        for (int r = 0; r < 16; ++r) mv = fmaxf(mv, fmaxf(st0[r], st1[r]));
        mv = fmaxf(mv, __shfl_xor(mv, 32));
        const float mnew = fmaxf(m_run, mv);
        const float alpha = exp2f(m_run - mnew);
        m_run = mnew;
        float sum = 0.f;
#pragma unroll
        for (int r = 0; r < 16; ++r) {
          st0[r] = exp2f(st0[r] - mnew);
          st1[r] = exp2f(st1[r] - mnew);
          sum += st0[r] + st1[r];
        }
        sum += __shfl_xor(sum, 32);
        l_run = l_run * alpha + sum;
        o0 = o0 * alpha;
        o1 = o1 * alpha;

        uint pk_[16];
#pragma unroll
        for (int j = 0; j < 8; ++j) pk_[j] = cvt_pk_bf16(st0[2 * j], st0[2 * j + 1]);
#pragma unroll
        for (int j = 0; j < 8; ++j) pk_[8 + j] = cvt_pk_bf16(st1[2 * j], st1[2 * j + 1]);
        pl32swap(pk_[0], pk_[2]);  pl32swap(pk_[1], pk_[3]);
        pl32swap(pk_[4], pk_[6]);  pl32swap(pk_[5], pk_[7]);
        pl32swap(pk_[8], pk_[10]); pl32swap(pk_[9], pk_[11]);
        pl32swap(pk_[12], pk_[14]); pl32swap(pk_[13], pk_[15]);
        uint4_t paw[4];
#pragma unroll
        for (int f = 0; f < 4; ++f)
          paw[f] = (uint4_t){pk_[4 * f], pk_[4 * f + 1], pk_[4 * f + 2], pk_[4 * f + 3]};

#pragma unroll
        for (int kb = 0; kb < 4; ++kb) {
          const short8_t pa = *(const short8_t*)&paw[kb];
          const int off = (kb * 32 + hh * 16) ^ xs;
          const short8_t vf0 = *(const short8_t*)(Vc + l31 * 128 + off);
          const short8_t vf1 = *(const short8_t*)(Vc + (32 + l31) * 128 + off);
          o0 = __builtin_amdgcn_mfma_f32_32x32x16_bf16(vf0, pa, o0, 0, 0, 0);
          o1 = __builtin_amdgcn_mfma_f32_32x32x16_bf16(vf1, pa, o1, 0, 0, 0);
        }
      }

      __syncthreads();
      cur ^= 1;
    }

    {
      short* ow = lds + w * 2048;
      const float inv = 1.0f / l_run;
#pragma unroll
      for (int r = 0; r < 16; ++r) {
        const int d = (r & 3) + 8 * (r >> 2) + 4 * hh;
        const int x = (l31 & 7) << 4;
        *(short*)((char*)ow + l31 * 128 + ((d * 2) ^ x)) = f2bf(o0[r] * inv);
        *(short*)((char*)ow + l31 * 128 + (((d + 32) * 2) ^ x)) = f2bf(o1[r] * inv);
      }
#pragma unroll
      for (int pz = 0; pz < 4; ++pz) {
        const int qloc = pz * 8 + (lane >> 3);
        const int sbyte = (lane & 7) * 16;
        const short8_t vv = *(const short8_t*)((char*)ow + qloc * 128 + (sbyte ^ ((qloc & 7) << 4)));
        *(short8_t*)(Og + ((size_t)(b * S_ + q0 + w * 32 + qloc)) * E_ + h * 64 + (lane & 7) * 8) = vv;
      }
    }
    __syncthreads();
  }
}

// ---------------- launch ----------------
extern "C" void kernel_launch(void* const* d_in, const int* in_sizes, int n_in,
                              void* d_out, int out_size, void* d_ws, size_t ws_size,
                              hipStream_t stream) {
  const float* X  = (const float*)d_in[0];
  const float* Wq = (const float*)d_in[1];
  const float* bq = (const float*)d_in[2];
  const float* Wk = (const float*)d_in[3];
  const float* bk = (const float*)d_in[4];
  const float* Wv = (const float*)d_in[5];
  const float* bv = (const float*)d_in[6];
  const float* Wo = (const float*)d_in[7];
  const float* bo = (const float*)d_in[8];

  const size_t NX = (size_t)B_ * S_ * E_;  // 8388608
  const size_t NW = (size_t)E_ * E_;       // 4194304

  short* ws = (short*)d_ws;
  short* Xb = ws;            // [B*S, E] bf16
  short* Wb = Xb + NX;       // 3*NW: Wq|Wk|Wv (first NW reused for Wo later)
  short* Kb = Wb + 3 * NW;   // [B*S, E]
  short* Vb = Kb + NX;       // V^T [b*E+n][S]
  short* Qb = (short*)d_out; // Q (scaled) parked in d_out
  short* Ab = Xb;            // attention output reuses X

  (void)hipFuncSetAttribute((const void*)gemm384_qkv,
                            hipFuncAttributeMaxDynamicSharedMemorySize, 131072);
  (void)hipFuncSetAttribute((const void*)gemm_o8,
                            hipFuncAttributeMaxDynamicSharedMemorySize, 98304);

  cast_bf16_kernel<<<2048, 256, 0, stream>>>(X, Xb, (int)(NX / 4));
  cast3_bf16<<<3072, 256, 0, stream>>>(Wq, Wk, Wv, Wb);

  gemm384_qkv<<<dim3(16, 32), 512, 131072, stream>>>(Xb, Wb, bq, bk, bv, Qb, Kb, Vb);

  cast_bf16_kernel<<<1024, 256, 0, stream>>>(Wo, Wb, (int)(NW / 4));

  attn_fwd<<<dim3(B_ * H_, 4), 512, 0, stream>>>(Qb, Kb, Vb, Ab);

  gemm_o8<<<dim3(E_ / 256, B_ * S_ / 128), 512, 98304, stream>>>(Ab, Wb, bo, (float*)d_out);
}